// Round 1
// baseline (705.194 us; speedup 1.0000x reference)
//
#include <hip/hip_runtime.h>

#define NNODES 50000
#define NEDGES 800000

// ---------------- CSR build ----------------

__global__ void zero_kernel(int* __restrict__ p, int n) {
    int i = blockIdx.x * blockDim.x + threadIdx.x;
    if (i < n) p[i] = 0;
}

__global__ void count_kernel(const int* __restrict__ dst, int* __restrict__ cnt, int e) {
    int i = blockIdx.x * blockDim.x + threadIdx.x;
    if (i < e) atomicAdd(&cnt[dst[i]], 1);
}

// single-block exclusive scan over N counts -> row_ptr, cursor copy, dinv = rsqrt(deg+1)
__global__ __launch_bounds__(1024) void scan_kernel(const int* __restrict__ cnt,
                                                    int* __restrict__ rp,
                                                    int* __restrict__ cursor,
                                                    float* __restrict__ dinv) {
    __shared__ int partial[1024];
    const int t = threadIdx.x;
    const int chunk = (NNODES + 1023) / 1024;
    const int beg = t * chunk;
    const int end = min(beg + chunk, NNODES);
    int s = 0;
    for (int i = beg; i < end; ++i) s += cnt[i];
    partial[t] = s;
    __syncthreads();
    for (int off = 1; off < 1024; off <<= 1) {
        int v = (t >= off) ? partial[t - off] : 0;
        __syncthreads();
        partial[t] += v;
        __syncthreads();
    }
    int run = (t > 0) ? partial[t - 1] : 0;
    for (int i = beg; i < end; ++i) {
        int c = cnt[i];
        rp[i] = run;
        cursor[i] = run;
        dinv[i] = rsqrtf((float)(c + 1));   // +1 self loop; always > 0
        run += c;
    }
    if (t == 1023) rp[NNODES] = run;
}

__global__ void fill_kernel(const int* __restrict__ src, const int* __restrict__ dst,
                            int* __restrict__ cursor, int* __restrict__ col, int e) {
    int i = blockIdx.x * blockDim.x + threadIdx.x;
    if (i < e) {
        int p = atomicAdd(&cursor[dst[i]], 1);
        col[p] = src[i];
    }
}

// ---------------- gather aggregation ----------------
// out[d] = dinv[d] * ( sum_{s in N(d)} dinv[s]*in[s]  +  dinv[d]*in[d] ) [+ bias] [relu]

template <int VEC>
__device__ inline void vloadf(float (&d)[VEC], const float* __restrict__ p) {
    if constexpr (VEC == 4) { float4 t = *(const float4*)p; d[0]=t.x; d[1]=t.y; d[2]=t.z; d[3]=t.w; }
    else if constexpr (VEC == 2) { float2 t = *(const float2*)p; d[0]=t.x; d[1]=t.y; }
    else { d[0] = *p; }
}
template <int VEC>
__device__ inline void vstoref(float* __restrict__ p, const float (&d)[VEC]) {
    if constexpr (VEC == 4) { *(float4*)p = make_float4(d[0], d[1], d[2], d[3]); }
    else if constexpr (VEC == 2) { *(float2*)p = make_float2(d[0], d[1]); }
    else { *p = d[0]; }
}

template <int F, int VEC, bool RELU, bool HAS_BIAS>
__global__ __launch_bounds__(256) void agg_kernel(const float* __restrict__ in,
                                                  float* __restrict__ out,
                                                  const int* __restrict__ rp,
                                                  const int* __restrict__ colidx,
                                                  const float* __restrict__ dinv,
                                                  const float* __restrict__ bias) {
    const int wave = threadIdx.x >> 6;
    const int lane = threadIdx.x & 63;
    const int d = blockIdx.x * 4 + wave;
    if (d >= NNODES) return;
    constexpr int LANES = F / VEC;
    if (lane >= LANES) return;                 // tail lanes idle (F=40 case)
    const int off = lane * VEC;

    const float dv = dinv[d];
    float acc[VEC];
    vloadf<VEC>(acc, in + (size_t)d * F + off);
#pragma unroll
    for (int v = 0; v < VEC; ++v) acc[v] *= dv;   // self-loop term dinv[d]*in[d]

    int j = rp[d];
    const int end = rp[d + 1];
    for (; j + 4 <= end; j += 4) {
        const int c0 = colidx[j + 0], c1 = colidx[j + 1], c2 = colidx[j + 2], c3 = colidx[j + 3];
        const float w0 = dinv[c0], w1 = dinv[c1], w2 = dinv[c2], w3 = dinv[c3];
        float t0[VEC], t1[VEC], t2[VEC], t3[VEC];
        vloadf<VEC>(t0, in + (size_t)c0 * F + off);
        vloadf<VEC>(t1, in + (size_t)c1 * F + off);
        vloadf<VEC>(t2, in + (size_t)c2 * F + off);
        vloadf<VEC>(t3, in + (size_t)c3 * F + off);
#pragma unroll
        for (int v = 0; v < VEC; ++v) acc[v] += w0 * t0[v] + w1 * t1[v] + w2 * t2[v] + w3 * t3[v];
    }
    for (; j < end; ++j) {
        const int c = colidx[j];
        const float wc = dinv[c];
        float t[VEC];
        vloadf<VEC>(t, in + (size_t)c * F + off);
#pragma unroll
        for (int v = 0; v < VEC; ++v) acc[v] += wc * t[v];
    }

    float res[VEC];
#pragma unroll
    for (int v = 0; v < VEC; ++v) {
        float r = dv * acc[v];
        if constexpr (HAS_BIAS) r += bias[off + v];
        if constexpr (RELU) r = fmaxf(r, 0.0f);
        res[v] = r;
    }
    vstoref<VEC>(out + (size_t)d * F + off, res);
}

// ---------------- fp32 register-tiled GEMM ----------------
// C[N,M] = A[N,K] @ W[K,M]  (+bias, relu if BIAS_RELU)

template <int BM, int BN, int BK, int TM, int TN, bool BIAS_RELU>
__global__ __launch_bounds__(256) void gemm_kernel(const float* __restrict__ A,
                                                   const float* __restrict__ W,
                                                   const float* __restrict__ bias,
                                                   float* __restrict__ C,
                                                   int Nrows, int K, int M) {
    constexpr int TX = BN / TN;
    constexpr int TY = BM / TM;
    static_assert(TX * TY == 256, "thread grid must be 256");
    constexpr int A_LOADS = (BM * BK) / (256 * 4);
    constexpr int W_LOADS = (BN * BK) / (256 * 4);
    static_assert(A_LOADS >= 1 && W_LOADS >= 1, "tile too small");

    const int tid = threadIdx.x;
    const int tx = tid % TX;
    const int ty = tid / TX;
    const int r0 = blockIdx.x * BM;
    const int c0 = blockIdx.y * BN;

    __shared__ float As[BK][BM + 4];   // +4 keeps 16B alignment, breaks bank stride
    __shared__ float Ws[BK][BN];

    float acc[TM][TN] = {};

    for (int k0 = 0; k0 < K; k0 += BK) {
        // A tile: float4 along k, transpose into As[k][row]
#pragma unroll
        for (int l = 0; l < A_LOADS; ++l) {
            const int idx = tid + l * 256;
            const int row = idx / (BK / 4);
            const int kq = idx % (BK / 4);
            float4 v = make_float4(0.f, 0.f, 0.f, 0.f);
            const int gr = r0 + row;
            if (gr < Nrows) v = *(const float4*)(A + (size_t)gr * K + k0 + kq * 4);
            As[kq * 4 + 0][row] = v.x;
            As[kq * 4 + 1][row] = v.y;
            As[kq * 4 + 2][row] = v.z;
            As[kq * 4 + 3][row] = v.w;
        }
        // W tile: float4 along columns
#pragma unroll
        for (int l = 0; l < W_LOADS; ++l) {
            const int idx = tid + l * 256;
            const int kk = idx / (BN / 4);
            const int cq = idx % (BN / 4);
            const int gc = c0 + cq * 4;
            float4 v;
            const float* wrow = W + (size_t)(k0 + kk) * M;
            if (gc + 3 < M) {
                v = *(const float4*)(wrow + gc);
            } else {
                v.x = (gc + 0 < M) ? wrow[gc + 0] : 0.f;
                v.y = (gc + 1 < M) ? wrow[gc + 1] : 0.f;
                v.z = (gc + 2 < M) ? wrow[gc + 2] : 0.f;
                v.w = (gc + 3 < M) ? wrow[gc + 3] : 0.f;
            }
            *(float4*)&Ws[kk][cq * 4] = v;
        }
        __syncthreads();

#pragma unroll
        for (int kk = 0; kk < BK; ++kk) {
            float a[TM], b[TN];
#pragma unroll
            for (int i = 0; i < TM; ++i) a[i] = As[kk][ty * TM + i];
#pragma unroll
            for (int j = 0; j < TN; ++j) b[j] = Ws[kk][tx * TN + j];
#pragma unroll
            for (int i = 0; i < TM; ++i)
#pragma unroll
                for (int j = 0; j < TN; ++j) acc[i][j] += a[i] * b[j];
        }
        __syncthreads();
    }

#pragma unroll
    for (int i = 0; i < TM; ++i) {
        const int gr = r0 + ty * TM + i;
        if (gr >= Nrows) continue;
#pragma unroll
        for (int j = 0; j < TN; ++j) {
            const int gc = c0 + tx * TN + j;
            if (gc >= M) continue;
            float v = acc[i][j];
            if constexpr (BIAS_RELU) v = fmaxf(v + bias[gc], 0.0f);
            C[(size_t)gr * M + gc] = v;
        }
    }
}

// ---------------- launch ----------------

extern "C" void kernel_launch(void* const* d_in, const int* in_sizes, int n_in,
                              void* d_out, int out_size, void* d_ws, size_t ws_size,
                              hipStream_t stream) {
    const float* x  = (const float*)d_in[0];
    const int* ei   = (const int*)d_in[1];
    const float* W1 = (const float*)d_in[2];
    const float* b1 = (const float*)d_in[3];
    const float* W2 = (const float*)d_in[4];
    const float* b2 = (const float*)d_in[5];
    const float* W3 = (const float*)d_in[6];
    const float* b3 = (const float*)d_in[7];
    const float* W4 = (const float*)d_in[8];
    const float* b4 = (const float*)d_in[9];
    float* out = (float*)d_out;
    const int* esrc = ei;            // edge_index[0] = message sources
    const int* edst = ei + NEDGES;   // edge_index[1] = aggregation targets

    char* w = (char*)d_ws;
    auto alloc = [&](size_t bytes) -> void* {
        void* p = (void*)w;
        w += (bytes + 255) & ~(size_t)255;
        return p;
    };
    int* cnt    = (int*)alloc((size_t)NNODES * 4);
    int* rp     = (int*)alloc((size_t)(NNODES + 1) * 4);
    int* cursor = (int*)alloc((size_t)NNODES * 4);
    int* col    = (int*)alloc((size_t)NEDGES * 4);
    float* dinv = (float*)alloc((size_t)NNODES * 4);
    float* B0   = (float*)alloc((size_t)NNODES * 256 * 4);  // widest buffer (h1)
    float* B1   = (float*)alloc((size_t)NNODES * 128 * 4);
    float* B2   = (float*)alloc((size_t)NNODES * 128 * 4);

    // CSR build (per call; ws is re-poisoned every launch)
    zero_kernel<<<(NNODES + 255) / 256, 256, 0, stream>>>(cnt, NNODES);
    count_kernel<<<(NEDGES + 255) / 256, 256, 0, stream>>>(edst, cnt, NEDGES);
    scan_kernel<<<1, 1024, 0, stream>>>(cnt, rp, cursor, dinv);
    fill_kernel<<<(NEDGES + 255) / 256, 256, 0, stream>>>(esrc, edst, cursor, col, NEDGES);

    const int aggGrid = (NNODES + 3) / 4;

    // Layer 1: aggregate FIRST in dim 128 (linearity), then GEMM+bias+relu
    agg_kernel<128, 2, false, false><<<aggGrid, 256, 0, stream>>>(x, B2, rp, col, dinv, nullptr);
    gemm_kernel<128, 128, 16, 8, 8, true>
        <<<dim3((NNODES + 127) / 128, 2), 256, 0, stream>>>(B2, W1, b1, B0, NNODES, 128, 256);

    // Layer 2: transform first (256->128), then aggregate+bias+relu
    gemm_kernel<128, 128, 16, 8, 8, false>
        <<<dim3((NNODES + 127) / 128, 1), 256, 0, stream>>>(B0, W2, nullptr, B1, NNODES, 256, 128);
    agg_kernel<128, 2, true, true><<<aggGrid, 256, 0, stream>>>(B1, B2, rp, col, dinv, b2);

    // Layer 3: transform first (128->64), aggregate+bias+relu
    gemm_kernel<64, 64, 16, 4, 4, false>
        <<<dim3((NNODES + 63) / 64, 1), 256, 0, stream>>>(B2, W3, nullptr, B0, NNODES, 128, 64);
    agg_kernel<64, 1, true, true><<<aggGrid, 256, 0, stream>>>(B0, B1, rp, col, dinv, b3);

    // Layer 4: transform first (64->40), aggregate+bias (no relu) -> d_out
    gemm_kernel<64, 64, 16, 4, 4, false>
        <<<dim3((NNODES + 63) / 64, 1), 256, 0, stream>>>(B1, W4, nullptr, B0, NNODES, 64, 40);
    agg_kernel<40, 1, false, true><<<aggGrid, 256, 0, stream>>>(B0, out, rp, col, dinv, b4);
}

// Round 2
// 571.641 us; speedup vs baseline: 1.2336x; 1.2336x over previous
//
#include <hip/hip_runtime.h>

#define NNODES 50000
#define NEDGES 800000
#define SCAN_NBLK ((NNODES + 255) / 256)   // 196

// ---------------- CSR build ----------------

__global__ void zero_kernel(int* __restrict__ p, int n) {
    int i = blockIdx.x * blockDim.x + threadIdx.x;
    if (i < n) p[i] = 0;
}

__global__ void count_kernel(const int* __restrict__ dst, int* __restrict__ cnt, int e) {
    int i = blockIdx.x * blockDim.x + threadIdx.x;
    if (i < e) atomicAdd(&cnt[dst[i]], 1);
}

// Phase 1: per-block (256 elems) reduction of cnt -> bsum[block]
__global__ __launch_bounds__(256) void scan1_kernel(const int* __restrict__ cnt,
                                                    int* __restrict__ bsum) {
    const int i = blockIdx.x * 256 + threadIdx.x;
    int v = (i < NNODES) ? cnt[i] : 0;
#pragma unroll
    for (int off = 32; off > 0; off >>= 1) v += __shfl_down(v, off, 64);
    __shared__ int wsum[4];
    if ((threadIdx.x & 63) == 0) wsum[threadIdx.x >> 6] = v;
    __syncthreads();
    if (threadIdx.x == 0) bsum[blockIdx.x] = wsum[0] + wsum[1] + wsum[2] + wsum[3];
}

// Phase 2: single tiny block scans the 196 block sums -> exclusive boff; total -> rp[N]
__global__ __launch_bounds__(256) void scan2_kernel(const int* __restrict__ bsum,
                                                    int* __restrict__ boff,
                                                    int* __restrict__ rp_last) {
    __shared__ int s[256];
    const int t = threadIdx.x;
    s[t] = (t < SCAN_NBLK) ? bsum[t] : 0;
    __syncthreads();
    for (int off = 1; off < 256; off <<= 1) {
        int v = (t >= off) ? s[t - off] : 0;
        __syncthreads();
        s[t] += v;
        __syncthreads();
    }
    if (t < SCAN_NBLK) boff[t] = (t > 0) ? s[t - 1] : 0;
    if (t == 255) rp_last[0] = s[255];
}

// Phase 3: per-block exclusive scan + block offset -> rp, cursor, dinv
__global__ __launch_bounds__(256) void scan3_kernel(const int* __restrict__ cnt,
                                                    const int* __restrict__ boff,
                                                    int* __restrict__ rp,
                                                    int* __restrict__ cursor,
                                                    float* __restrict__ dinv) {
    __shared__ int s[256];
    const int t = threadIdx.x;
    const int i = blockIdx.x * 256 + t;
    const int c = (i < NNODES) ? cnt[i] : 0;
    s[t] = c;
    __syncthreads();
    for (int off = 1; off < 256; off <<= 1) {
        int v = (t >= off) ? s[t - off] : 0;
        __syncthreads();
        s[t] += v;
        __syncthreads();
    }
    if (i < NNODES) {
        const int excl = boff[blockIdx.x] + s[t] - c;
        rp[i] = excl;
        cursor[i] = excl;
        dinv[i] = rsqrtf((float)(c + 1));   // +1 self loop; always > 0
    }
}

__global__ void fill_kernel(const int* __restrict__ src, const int* __restrict__ dst,
                            int* __restrict__ cursor, int* __restrict__ col, int e) {
    int i = blockIdx.x * blockDim.x + threadIdx.x;
    if (i < e) {
        int p = atomicAdd(&cursor[dst[i]], 1);
        col[p] = src[i];
    }
}

// ---------------- gather aggregation ----------------
// out[d] = dinv[d] * ( sum_{s in N(d)} dinv[s]*in[s]  +  dinv[d]*in[d] ) [+ bias] [relu]

template <int VEC>
__device__ inline void vloadf(float (&d)[VEC], const float* __restrict__ p) {
    if constexpr (VEC == 4) { float4 t = *(const float4*)p; d[0]=t.x; d[1]=t.y; d[2]=t.z; d[3]=t.w; }
    else if constexpr (VEC == 2) { float2 t = *(const float2*)p; d[0]=t.x; d[1]=t.y; }
    else { d[0] = *p; }
}
template <int VEC>
__device__ inline void vstoref(float* __restrict__ p, const float (&d)[VEC]) {
    if constexpr (VEC == 4) { *(float4*)p = make_float4(d[0], d[1], d[2], d[3]); }
    else if constexpr (VEC == 2) { *(float2*)p = make_float2(d[0], d[1]); }
    else { *p = d[0]; }
}

template <int F, int VEC, bool RELU, bool HAS_BIAS>
__global__ __launch_bounds__(256) void agg_kernel(const float* __restrict__ in,
                                                  float* __restrict__ out,
                                                  const int* __restrict__ rp,
                                                  const int* __restrict__ colidx,
                                                  const float* __restrict__ dinv,
                                                  const float* __restrict__ bias) {
    const int wave = threadIdx.x >> 6;
    const int lane = threadIdx.x & 63;
    const int d = blockIdx.x * 4 + wave;
    if (d >= NNODES) return;
    constexpr int LANES = F / VEC;
    if (lane >= LANES) return;                 // tail lanes idle (F=40 case)
    const int off = lane * VEC;

    const float dv = dinv[d];
    float acc[VEC];
    vloadf<VEC>(acc, in + (size_t)d * F + off);
#pragma unroll
    for (int v = 0; v < VEC; ++v) acc[v] *= dv;   // self-loop term dinv[d]*in[d]

    int j = rp[d];
    const int end = rp[d + 1];
    for (; j + 4 <= end; j += 4) {
        const int c0 = colidx[j + 0], c1 = colidx[j + 1], c2 = colidx[j + 2], c3 = colidx[j + 3];
        const float w0 = dinv[c0], w1 = dinv[c1], w2 = dinv[c2], w3 = dinv[c3];
        float t0[VEC], t1[VEC], t2[VEC], t3[VEC];
        vloadf<VEC>(t0, in + (size_t)c0 * F + off);
        vloadf<VEC>(t1, in + (size_t)c1 * F + off);
        vloadf<VEC>(t2, in + (size_t)c2 * F + off);
        vloadf<VEC>(t3, in + (size_t)c3 * F + off);
#pragma unroll
        for (int v = 0; v < VEC; ++v) acc[v] += w0 * t0[v] + w1 * t1[v] + w2 * t2[v] + w3 * t3[v];
    }
    for (; j < end; ++j) {
        const int c = colidx[j];
        const float wc = dinv[c];
        float t[VEC];
        vloadf<VEC>(t, in + (size_t)c * F + off);
#pragma unroll
        for (int v = 0; v < VEC; ++v) acc[v] += wc * t[v];
    }

    float res[VEC];
#pragma unroll
    for (int v = 0; v < VEC; ++v) {
        float r = dv * acc[v];
        if constexpr (HAS_BIAS) r += bias[off + v];
        if constexpr (RELU) r = fmaxf(r, 0.0f);
        res[v] = r;
    }
    vstoref<VEC>(out + (size_t)d * F + off, res);
}

// ---------------- fp32 register-tiled GEMM ----------------
// C[N,M] = A[N,K] @ W[K,M]  (+bias, relu if BIAS_RELU)

template <int BM, int BN, int BK, int TM, int TN, bool BIAS_RELU>
__global__ __launch_bounds__(256) void gemm_kernel(const float* __restrict__ A,
                                                   const float* __restrict__ W,
                                                   const float* __restrict__ bias,
                                                   float* __restrict__ C,
                                                   int Nrows, int K, int M) {
    constexpr int TX = BN / TN;
    constexpr int TY = BM / TM;
    static_assert(TX * TY == 256, "thread grid must be 256");
    constexpr int A_LOADS = (BM * BK) / (256 * 4);
    constexpr int W_LOADS = (BN * BK) / (256 * 4);
    static_assert(A_LOADS >= 1 && W_LOADS >= 1, "tile too small");

    const int tid = threadIdx.x;
    const int tx = tid % TX;
    const int ty = tid / TX;
    const int r0 = blockIdx.x * BM;
    const int c0 = blockIdx.y * BN;

    __shared__ float As[BK][BM + 4];   // +4 keeps 16B alignment, breaks bank stride
    __shared__ float Ws[BK][BN];

    float acc[TM][TN] = {};

    for (int k0 = 0; k0 < K; k0 += BK) {
        // A tile: float4 along k, transpose into As[k][row]
#pragma unroll
        for (int l = 0; l < A_LOADS; ++l) {
            const int idx = tid + l * 256;
            const int row = idx / (BK / 4);
            const int kq = idx % (BK / 4);
            float4 v = make_float4(0.f, 0.f, 0.f, 0.f);
            const int gr = r0 + row;
            if (gr < Nrows) v = *(const float4*)(A + (size_t)gr * K + k0 + kq * 4);
            As[kq * 4 + 0][row] = v.x;
            As[kq * 4 + 1][row] = v.y;
            As[kq * 4 + 2][row] = v.z;
            As[kq * 4 + 3][row] = v.w;
        }
        // W tile: float4 along columns
#pragma unroll
        for (int l = 0; l < W_LOADS; ++l) {
            const int idx = tid + l * 256;
            const int kk = idx / (BN / 4);
            const int cq = idx % (BN / 4);
            const int gc = c0 + cq * 4;
            float4 v;
            const float* wrow = W + (size_t)(k0 + kk) * M;
            if (gc + 3 < M) {
                v = *(const float4*)(wrow + gc);
            } else {
                v.x = (gc + 0 < M) ? wrow[gc + 0] : 0.f;
                v.y = (gc + 1 < M) ? wrow[gc + 1] : 0.f;
                v.z = (gc + 2 < M) ? wrow[gc + 2] : 0.f;
                v.w = (gc + 3 < M) ? wrow[gc + 3] : 0.f;
            }
            *(float4*)&Ws[kk][cq * 4] = v;
        }
        __syncthreads();

#pragma unroll
        for (int kk = 0; kk < BK; ++kk) {
            float a[TM], b[TN];
#pragma unroll
            for (int i = 0; i < TM; ++i) a[i] = As[kk][ty * TM + i];
#pragma unroll
            for (int j = 0; j < TN; ++j) b[j] = Ws[kk][tx * TN + j];
#pragma unroll
            for (int i = 0; i < TM; ++i)
#pragma unroll
                for (int j = 0; j < TN; ++j) acc[i][j] += a[i] * b[j];
        }
        __syncthreads();
    }

#pragma unroll
    for (int i = 0; i < TM; ++i) {
        const int gr = r0 + ty * TM + i;
        if (gr >= Nrows) continue;
#pragma unroll
        for (int j = 0; j < TN; ++j) {
            const int gc = c0 + tx * TN + j;
            if (gc >= M) continue;
            float v = acc[i][j];
            if constexpr (BIAS_RELU) v = fmaxf(v + bias[gc], 0.0f);
            C[(size_t)gr * M + gc] = v;
        }
    }
}

// ---------------- launch ----------------

extern "C" void kernel_launch(void* const* d_in, const int* in_sizes, int n_in,
                              void* d_out, int out_size, void* d_ws, size_t ws_size,
                              hipStream_t stream) {
    const float* x  = (const float*)d_in[0];
    const int* ei   = (const int*)d_in[1];
    const float* W1 = (const float*)d_in[2];
    const float* b1 = (const float*)d_in[3];
    const float* W2 = (const float*)d_in[4];
    const float* b2 = (const float*)d_in[5];
    const float* W3 = (const float*)d_in[6];
    const float* b3 = (const float*)d_in[7];
    const float* W4 = (const float*)d_in[8];
    const float* b4 = (const float*)d_in[9];
    float* out = (float*)d_out;
    const int* esrc = ei;            // edge_index[0] = message sources
    const int* edst = ei + NEDGES;   // edge_index[1] = aggregation targets

    char* w = (char*)d_ws;
    auto alloc = [&](size_t bytes) -> void* {
        void* p = (void*)w;
        w += (bytes + 255) & ~(size_t)255;
        return p;
    };
    int* cnt    = (int*)alloc((size_t)NNODES * 4);
    int* rp     = (int*)alloc((size_t)(NNODES + 1) * 4);
    int* cursor = (int*)alloc((size_t)NNODES * 4);
    int* col    = (int*)alloc((size_t)NEDGES * 4);
    float* dinv = (float*)alloc((size_t)NNODES * 4);
    int* bsum   = (int*)alloc((size_t)SCAN_NBLK * 4);
    int* boff   = (int*)alloc((size_t)SCAN_NBLK * 4);
    float* B0   = (float*)alloc((size_t)NNODES * 256 * 4);  // widest buffer (h1)
    float* B1   = (float*)alloc((size_t)NNODES * 128 * 4);
    float* B2   = (float*)alloc((size_t)NNODES * 128 * 4);

    // CSR build (per call; ws is re-poisoned every launch)
    zero_kernel<<<(NNODES + 255) / 256, 256, 0, stream>>>(cnt, NNODES);
    count_kernel<<<(NEDGES + 255) / 256, 256, 0, stream>>>(edst, cnt, NEDGES);
    scan1_kernel<<<SCAN_NBLK, 256, 0, stream>>>(cnt, bsum);
    scan2_kernel<<<1, 256, 0, stream>>>(bsum, boff, rp + NNODES);
    scan3_kernel<<<SCAN_NBLK, 256, 0, stream>>>(cnt, boff, rp, cursor, dinv);
    fill_kernel<<<(NEDGES + 255) / 256, 256, 0, stream>>>(esrc, edst, cursor, col, NEDGES);

    const int aggGrid = (NNODES + 3) / 4;

    // Layer 1: aggregate FIRST in dim 128 (linearity), then GEMM+bias+relu
    agg_kernel<128, 2, false, false><<<aggGrid, 256, 0, stream>>>(x, B2, rp, col, dinv, nullptr);
    gemm_kernel<128, 128, 16, 8, 8, true>
        <<<dim3((NNODES + 127) / 128, 2), 256, 0, stream>>>(B2, W1, b1, B0, NNODES, 128, 256);

    // Layer 2: transform first (256->128), then aggregate+bias+relu
    gemm_kernel<128, 128, 16, 8, 8, false>
        <<<dim3((NNODES + 127) / 128, 1), 256, 0, stream>>>(B0, W2, nullptr, B1, NNODES, 256, 128);
    agg_kernel<128, 2, true, true><<<aggGrid, 256, 0, stream>>>(B1, B2, rp, col, dinv, b2);

    // Layer 3: transform first (128->64), aggregate+bias+relu
    gemm_kernel<64, 64, 16, 4, 4, false>
        <<<dim3((NNODES + 63) / 64, 1), 256, 0, stream>>>(B2, W3, nullptr, B0, NNODES, 128, 64);
    agg_kernel<64, 1, true, true><<<aggGrid, 256, 0, stream>>>(B0, B1, rp, col, dinv, b3);

    // Layer 4: transform first (64->40), aggregate+bias (no relu) -> d_out
    gemm_kernel<64, 64, 16, 4, 4, false>
        <<<dim3((NNODES + 63) / 64, 1), 256, 0, stream>>>(B1, W4, nullptr, B0, NNODES, 64, 40);
    agg_kernel<40, 1, false, true><<<aggGrid, 256, 0, stream>>>(B0, out, rp, col, dinv, b4);
}

// Round 3
// 452.100 us; speedup vs baseline: 1.5598x; 1.2644x over previous
//
#include <hip/hip_runtime.h>
#include <stdint.h>

#define NNODES 50000
#define NEDGES 800000
#define SCAN_NBLK ((NNODES + 255) / 256)   // 196

typedef __attribute__((ext_vector_type(8))) short bf16x8;
typedef __attribute__((ext_vector_type(4))) float f32x4;

__device__ inline unsigned short f2bf(float f) {
    unsigned u = __float_as_uint(f);
    return (unsigned short)((u + 0x7fffu + ((u >> 16) & 1u)) >> 16);
}
__device__ inline float bf2f(unsigned short h) {
    return __uint_as_float(((unsigned)h) << 16);
}

// ---------------- CSR build ----------------

__global__ void zero_kernel(int* __restrict__ p, int n) {
    int i = blockIdx.x * blockDim.x + threadIdx.x;
    if (i < n) p[i] = 0;
}

__global__ void count_kernel(const int* __restrict__ dst, int* __restrict__ cnt, int e) {
    int i = blockIdx.x * blockDim.x + threadIdx.x;
    if (i < e) atomicAdd(&cnt[dst[i]], 1);
}

__global__ __launch_bounds__(256) void scan1_kernel(const int* __restrict__ cnt,
                                                    int* __restrict__ bsum) {
    const int i = blockIdx.x * 256 + threadIdx.x;
    int v = (i < NNODES) ? cnt[i] : 0;
#pragma unroll
    for (int off = 32; off > 0; off >>= 1) v += __shfl_down(v, off, 64);
    __shared__ int wsum[4];
    if ((threadIdx.x & 63) == 0) wsum[threadIdx.x >> 6] = v;
    __syncthreads();
    if (threadIdx.x == 0) bsum[blockIdx.x] = wsum[0] + wsum[1] + wsum[2] + wsum[3];
}

__global__ __launch_bounds__(256) void scan2_kernel(const int* __restrict__ bsum,
                                                    int* __restrict__ boff,
                                                    int* __restrict__ rp_last) {
    __shared__ int s[256];
    const int t = threadIdx.x;
    s[t] = (t < SCAN_NBLK) ? bsum[t] : 0;
    __syncthreads();
    for (int off = 1; off < 256; off <<= 1) {
        int v = (t >= off) ? s[t - off] : 0;
        __syncthreads();
        s[t] += v;
        __syncthreads();
    }
    if (t < SCAN_NBLK) boff[t] = (t > 0) ? s[t - 1] : 0;
    if (t == 255) rp_last[0] = s[255];
}

__global__ __launch_bounds__(256) void scan3_kernel(const int* __restrict__ cnt,
                                                    const int* __restrict__ boff,
                                                    int* __restrict__ rp,
                                                    int* __restrict__ cursor,
                                                    float* __restrict__ dinv) {
    __shared__ int s[256];
    const int t = threadIdx.x;
    const int i = blockIdx.x * 256 + t;
    const int c = (i < NNODES) ? cnt[i] : 0;
    s[t] = c;
    __syncthreads();
    for (int off = 1; off < 256; off <<= 1) {
        int v = (t >= off) ? s[t - off] : 0;
        __syncthreads();
        s[t] += v;
        __syncthreads();
    }
    if (i < NNODES) {
        const int excl = boff[blockIdx.x] + s[t] - c;
        rp[i] = excl;
        cursor[i] = excl;
        dinv[i] = rsqrtf((float)(c + 1));
    }
}

__global__ void fill_kernel(const int* __restrict__ src, const int* __restrict__ dst,
                            int* __restrict__ cursor, int* __restrict__ col, int e) {
    int i = blockIdx.x * blockDim.x + threadIdx.x;
    if (i < e) {
        int p = atomicAdd(&cursor[dst[i]], 1);
        col[p] = src[i];
    }
}

// ---------------- gather aggregation ----------------

template <int VEC>
__device__ inline void vloadf(float (&d)[VEC], const float* __restrict__ p) {
    if constexpr (VEC == 4) { float4 t = *(const float4*)p; d[0]=t.x; d[1]=t.y; d[2]=t.z; d[3]=t.w; }
    else if constexpr (VEC == 2) { float2 t = *(const float2*)p; d[0]=t.x; d[1]=t.y; }
    else { d[0] = *p; }
}
template <int VEC>
__device__ inline void vstoref(float* __restrict__ p, const float (&d)[VEC]) {
    if constexpr (VEC == 4) { *(float4*)p = make_float4(d[0], d[1], d[2], d[3]); }
    else if constexpr (VEC == 2) { *(float2*)p = make_float2(d[0], d[1]); }
    else { *p = d[0]; }
}

template <int F, int VEC, bool RELU, bool HAS_BIAS>
__global__ __launch_bounds__(256) void agg_kernel(const float* __restrict__ in,
                                                  float* __restrict__ out,
                                                  const int* __restrict__ rp,
                                                  const int* __restrict__ colidx,
                                                  const float* __restrict__ dinv,
                                                  const float* __restrict__ bias) {
    const int wave = threadIdx.x >> 6;
    const int lane = threadIdx.x & 63;
    const int d = blockIdx.x * 4 + wave;
    if (d >= NNODES) return;
    constexpr int LANES = F / VEC;
    if (lane >= LANES) return;
    const int off = lane * VEC;

    const float dv = dinv[d];
    float acc[VEC];
    vloadf<VEC>(acc, in + (size_t)d * F + off);
#pragma unroll
    for (int v = 0; v < VEC; ++v) acc[v] *= dv;

    int j = rp[d];
    const int end = rp[d + 1];
    for (; j + 4 <= end; j += 4) {
        const int c0 = colidx[j + 0], c1 = colidx[j + 1], c2 = colidx[j + 2], c3 = colidx[j + 3];
        const float w0 = dinv[c0], w1 = dinv[c1], w2 = dinv[c2], w3 = dinv[c3];
        float t0[VEC], t1[VEC], t2[VEC], t3[VEC];
        vloadf<VEC>(t0, in + (size_t)c0 * F + off);
        vloadf<VEC>(t1, in + (size_t)c1 * F + off);
        vloadf<VEC>(t2, in + (size_t)c2 * F + off);
        vloadf<VEC>(t3, in + (size_t)c3 * F + off);
#pragma unroll
        for (int v = 0; v < VEC; ++v) acc[v] += w0 * t0[v] + w1 * t1[v] + w2 * t2[v] + w3 * t3[v];
    }
    for (; j < end; ++j) {
        const int c = colidx[j];
        const float wc = dinv[c];
        float t[VEC];
        vloadf<VEC>(t, in + (size_t)c * F + off);
#pragma unroll
        for (int v = 0; v < VEC; ++v) acc[v] += wc * t[v];
    }

    float res[VEC];
#pragma unroll
    for (int v = 0; v < VEC; ++v) {
        float r = dv * acc[v];
        if constexpr (HAS_BIAS) r += bias[off + v];
        if constexpr (RELU) r = fmaxf(r, 0.0f);
        res[v] = r;
    }
    vstoref<VEC>(out + (size_t)d * F + off, res);
}

// ---------------- weight repack: W[K][M] fp32 -> split-bf16 fragment order ----
// Layout: [cb][ks][ct][lane][j]  (cb = n>>7, ks = k>>5, ct = (n>>4)&7,
//          lane = ((k>>3)&3)*16 + (n&15), j = k&7)

template <int K, int M>
__global__ __launch_bounds__(256) void repack_kernel(const float* __restrict__ W,
                                                     unsigned short* __restrict__ hi,
                                                     unsigned short* __restrict__ lo) {
    int i = blockIdx.x * 256 + threadIdx.x;
    if (i >= K * M) return;
    const int k = i / M, n = i % M;
    constexpr int KS = K / 32;
    const int cb = n >> 7;
    const int ct = (n >> 4) & 7;
    const int ln = ((k >> 3) & 3) * 16 + (n & 15);
    const int j  = k & 7;
    const int ks = k >> 5;
    const size_t o = ((((size_t)cb * KS + ks) * 8 + ct) * 64 + ln) * 8 + j;
    const float f = W[i];
    const unsigned short h = f2bf(f);
    hi[o] = h;
    lo[o] = f2bf(f - bf2f(h));
}

// ---------------- split-bf16 MFMA GEMM ----------------
// C[Nrows x M] = A[Nrows x K] (fp32, row-major) @ W (pre-packed hi/lo)
// Block: 128x128 tile, 4 waves each 64x64. BK=32. 3 MFMAs per frag pair.

template <int K, int M, bool BIAS_RELU>
__global__ __launch_bounds__(256) void mfma_gemm_kernel(const float* __restrict__ A,
                                                        const unsigned short* __restrict__ Whi,
                                                        const unsigned short* __restrict__ Wlo,
                                                        const float* __restrict__ bias,
                                                        float* __restrict__ C) {
    constexpr int KS = K / 32;
    __shared__ char lds[32768];
    char* Ahi = lds;              // 8KB: [rt(8)][lane(64)][8 bf16]
    char* Alo = lds + 8192;
    char* Bhi = lds + 16384;      // 8KB: [ct(8)][lane(64)][8 bf16]
    char* Blo = lds + 24576;

    const int t = threadIdx.x;
    const int lane = t & 63;
    const int w = t >> 6;
    const int wr = w >> 1, wc = w & 1;
    const int r0 = blockIdx.x * 128;
    const int n0 = blockIdx.y * 128;

    const unsigned short* bhg = Whi + (size_t)blockIdx.y * KS * 4096;
    const unsigned short* blg = Wlo + (size_t)blockIdx.y * KS * 4096;

    f32x4 acc[4][4];
#pragma unroll
    for (int i = 0; i < 4; ++i)
#pragma unroll
        for (int j = 0; j < 4; ++j) acc[i][j] = (f32x4){0.f, 0.f, 0.f, 0.f};

    for (int ks = 0; ks < KS; ++ks) {
        const int k0 = ks * 32;

        // B tiles: async global->LDS, already in fragment order (1KB per chunk)
        {
            const char* gh = (const char*)(bhg + (size_t)ks * 4096);
            const char* gl = (const char*)(blg + (size_t)ks * 4096);
#pragma unroll
            for (int c = 0; c < 2; ++c) {
                const int ct = w * 2 + c;
                __builtin_amdgcn_global_load_lds(
                    (const __attribute__((address_space(1))) void*)(gh + ct * 1024 + lane * 16),
                    (__attribute__((address_space(3))) void*)(Bhi + ct * 1024), 16, 0, 0);
                __builtin_amdgcn_global_load_lds(
                    (const __attribute__((address_space(1))) void*)(gl + ct * 1024 + lane * 16),
                    (__attribute__((address_space(3))) void*)(Blo + ct * 1024), 16, 0, 0);
            }
        }

        // A tile: fp32 global -> split bf16 -> LDS fragment order
        float4 av[4];
#pragma unroll
        for (int i = 0; i < 4; ++i) {
            const int q = t + i * 256;
            const int row = q >> 3;
            const int kq = (q & 7) * 4;
            const int gr = r0 + row;
            float4 v = make_float4(0.f, 0.f, 0.f, 0.f);
            if (gr < NNODES) v = *(const float4*)(A + (size_t)gr * K + k0 + kq);
            av[i] = v;
        }
#pragma unroll
        for (int i = 0; i < 4; ++i) {
            const int q = t + i * 256;
            const int row = q >> 3;
            const int kq = (q & 7) * 4;
            const int rt = row >> 4, m = row & 15, quad = kq >> 3, j0 = kq & 7;
            const int off = rt * 1024 + (quad * 16 + m) * 16 + j0 * 2;
            const float4 v = av[i];
            ushort4 h, l;
            h.x = f2bf(v.x); l.x = f2bf(v.x - bf2f(h.x));
            h.y = f2bf(v.y); l.y = f2bf(v.y - bf2f(h.y));
            h.z = f2bf(v.z); l.z = f2bf(v.z - bf2f(h.z));
            h.w = f2bf(v.w); l.w = f2bf(v.w - bf2f(h.w));
            *(ushort4*)(Ahi + off) = h;
            *(ushort4*)(Alo + off) = l;
        }
        __syncthreads();

        bf16x8 ah[4], al[4], bh[4], bl[4];
#pragma unroll
        for (int i = 0; i < 4; ++i) {
            ah[i] = *(const bf16x8*)(Ahi + (wr * 4 + i) * 1024 + lane * 16);
            al[i] = *(const bf16x8*)(Alo + (wr * 4 + i) * 1024 + lane * 16);
            bh[i] = *(const bf16x8*)(Bhi + (wc * 4 + i) * 1024 + lane * 16);
            bl[i] = *(const bf16x8*)(Blo + (wc * 4 + i) * 1024 + lane * 16);
        }
#pragma unroll
        for (int i = 0; i < 4; ++i)
#pragma unroll
            for (int j = 0; j < 4; ++j) {
                acc[i][j] = __builtin_amdgcn_mfma_f32_16x16x32_bf16(ah[i], bh[j], acc[i][j], 0, 0, 0);
                acc[i][j] = __builtin_amdgcn_mfma_f32_16x16x32_bf16(ah[i], bl[j], acc[i][j], 0, 0, 0);
                acc[i][j] = __builtin_amdgcn_mfma_f32_16x16x32_bf16(al[i], bh[j], acc[i][j], 0, 0, 0);
            }
        __syncthreads();
    }

    // epilogue: C/D layout col=lane&15, row=quad*4+reg  [m89-verified]
    const int quad = lane >> 4;
    const int cl = lane & 15;
#pragma unroll
    for (int i = 0; i < 4; ++i) {
#pragma unroll
        for (int j = 0; j < 4; ++j) {
            const int colg = n0 + wc * 64 + j * 16 + cl;
            float bv = 0.f;
            if constexpr (BIAS_RELU) bv = bias[colg];
#pragma unroll
            for (int r = 0; r < 4; ++r) {
                const int rowg = r0 + wr * 64 + i * 16 + quad * 4 + r;
                if (rowg < NNODES) {
                    float v = acc[i][j][r] + bv;
                    if constexpr (BIAS_RELU) v = fmaxf(v, 0.f);
                    C[(size_t)rowg * M + colg] = v;
                }
            }
        }
    }
}

// ---------------- fp32 register-tiled GEMM (layers 3-4) ----------------

template <int BM, int BN, int BK, int TM, int TN, bool BIAS_RELU>
__global__ __launch_bounds__(256) void gemm_kernel(const float* __restrict__ A,
                                                   const float* __restrict__ W,
                                                   const float* __restrict__ bias,
                                                   float* __restrict__ C,
                                                   int Nrows, int K, int M) {
    constexpr int TX = BN / TN;
    constexpr int TY = BM / TM;
    static_assert(TX * TY == 256, "thread grid must be 256");
    constexpr int A_LOADS = (BM * BK) / (256 * 4);
    constexpr int W_LOADS = (BN * BK) / (256 * 4);
    static_assert(A_LOADS >= 1 && W_LOADS >= 1, "tile too small");

    const int tid = threadIdx.x;
    const int tx = tid % TX;
    const int ty = tid / TX;
    const int r0 = blockIdx.x * BM;
    const int c0 = blockIdx.y * BN;

    __shared__ float As[BK][BM + 4];
    __shared__ float Ws[BK][BN];

    float acc[TM][TN] = {};

    for (int k0 = 0; k0 < K; k0 += BK) {
#pragma unroll
        for (int l = 0; l < A_LOADS; ++l) {
            const int idx = tid + l * 256;
            const int row = idx / (BK / 4);
            const int kq = idx % (BK / 4);
            float4 v = make_float4(0.f, 0.f, 0.f, 0.f);
            const int gr = r0 + row;
            if (gr < Nrows) v = *(const float4*)(A + (size_t)gr * K + k0 + kq * 4);
            As[kq * 4 + 0][row] = v.x;
            As[kq * 4 + 1][row] = v.y;
            As[kq * 4 + 2][row] = v.z;
            As[kq * 4 + 3][row] = v.w;
        }
#pragma unroll
        for (int l = 0; l < W_LOADS; ++l) {
            const int idx = tid + l * 256;
            const int kk = idx / (BN / 4);
            const int cq = idx % (BN / 4);
            const int gc = c0 + cq * 4;
            float4 v;
            const float* wrow = W + (size_t)(k0 + kk) * M;
            if (gc + 3 < M) {
                v = *(const float4*)(wrow + gc);
            } else {
                v.x = (gc + 0 < M) ? wrow[gc + 0] : 0.f;
                v.y = (gc + 1 < M) ? wrow[gc + 1] : 0.f;
                v.z = (gc + 2 < M) ? wrow[gc + 2] : 0.f;
                v.w = (gc + 3 < M) ? wrow[gc + 3] : 0.f;
            }
            *(float4*)&Ws[kk][cq * 4] = v;
        }
        __syncthreads();

#pragma unroll
        for (int kk = 0; kk < BK; ++kk) {
            float a[TM], b[TN];
#pragma unroll
            for (int i = 0; i < TM; ++i) a[i] = As[kk][ty * TM + i];
#pragma unroll
            for (int j = 0; j < TN; ++j) b[j] = Ws[kk][tx * TN + j];
#pragma unroll
            for (int i = 0; i < TM; ++i)
#pragma unroll
                for (int j = 0; j < TN; ++j) acc[i][j] += a[i] * b[j];
        }
        __syncthreads();
    }

#pragma unroll
    for (int i = 0; i < TM; ++i) {
        const int gr = r0 + ty * TM + i;
        if (gr >= Nrows) continue;
#pragma unroll
        for (int j = 0; j < TN; ++j) {
            const int gc = c0 + tx * TN + j;
            if (gc >= M) continue;
            float v = acc[i][j];
            if constexpr (BIAS_RELU) v = fmaxf(v + bias[gc], 0.0f);
            C[(size_t)gr * M + gc] = v;
        }
    }
}

// ---------------- launch ----------------

extern "C" void kernel_launch(void* const* d_in, const int* in_sizes, int n_in,
                              void* d_out, int out_size, void* d_ws, size_t ws_size,
                              hipStream_t stream) {
    const float* x  = (const float*)d_in[0];
    const int* ei   = (const int*)d_in[1];
    const float* W1 = (const float*)d_in[2];
    const float* b1 = (const float*)d_in[3];
    const float* W2 = (const float*)d_in[4];
    const float* b2 = (const float*)d_in[5];
    const float* W3 = (const float*)d_in[6];
    const float* b3 = (const float*)d_in[7];
    const float* W4 = (const float*)d_in[8];
    const float* b4 = (const float*)d_in[9];
    float* out = (float*)d_out;
    const int* esrc = ei;
    const int* edst = ei + NEDGES;

    char* w = (char*)d_ws;
    auto alloc = [&](size_t bytes) -> void* {
        void* p = (void*)w;
        w += (bytes + 255) & ~(size_t)255;
        return p;
    };
    int* cnt    = (int*)alloc((size_t)NNODES * 4);
    int* rp     = (int*)alloc((size_t)(NNODES + 1) * 4);
    int* cursor = (int*)alloc((size_t)NNODES * 4);
    int* col    = (int*)alloc((size_t)NEDGES * 4);
    float* dinv = (float*)alloc((size_t)NNODES * 4);
    int* bsum   = (int*)alloc((size_t)SCAN_NBLK * 4);
    int* boff   = (int*)alloc((size_t)SCAN_NBLK * 4);
    unsigned short* W1hi = (unsigned short*)alloc((size_t)128 * 256 * 2);
    unsigned short* W1lo = (unsigned short*)alloc((size_t)128 * 256 * 2);
    unsigned short* W2hi = (unsigned short*)alloc((size_t)256 * 128 * 2);
    unsigned short* W2lo = (unsigned short*)alloc((size_t)256 * 128 * 2);
    float* B0   = (float*)alloc((size_t)NNODES * 256 * 4);
    float* B1   = (float*)alloc((size_t)NNODES * 128 * 4);
    float* B2   = (float*)alloc((size_t)NNODES * 128 * 4);

    // weight repack (tiny)
    repack_kernel<128, 256><<<(128 * 256 + 255) / 256, 256, 0, stream>>>(W1, W1hi, W1lo);
    repack_kernel<256, 128><<<(256 * 128 + 255) / 256, 256, 0, stream>>>(W2, W2hi, W2lo);

    // CSR build
    zero_kernel<<<(NNODES + 255) / 256, 256, 0, stream>>>(cnt, NNODES);
    count_kernel<<<(NEDGES + 255) / 256, 256, 0, stream>>>(edst, cnt, NEDGES);
    scan1_kernel<<<SCAN_NBLK, 256, 0, stream>>>(cnt, bsum);
    scan2_kernel<<<1, 256, 0, stream>>>(bsum, boff, rp + NNODES);
    scan3_kernel<<<SCAN_NBLK, 256, 0, stream>>>(cnt, boff, rp, cursor, dinv);
    fill_kernel<<<(NEDGES + 255) / 256, 256, 0, stream>>>(esrc, edst, cursor, col, NEDGES);

    const int aggGrid = (NNODES + 3) / 4;
    const int rowBlks = (NNODES + 127) / 128;   // 391

    // Layer 1: aggregate first (dim 128), then MFMA GEMM 128->256 (+bias+relu)
    agg_kernel<128, 2, false, false><<<aggGrid, 256, 0, stream>>>(x, B2, rp, col, dinv, nullptr);
    mfma_gemm_kernel<128, 256, true>
        <<<dim3(rowBlks, 2), 256, 0, stream>>>(B2, W1hi, W1lo, b1, B0);

    // Layer 2: MFMA GEMM 256->128, then aggregate (+bias+relu)
    mfma_gemm_kernel<256, 128, false>
        <<<dim3(rowBlks, 1), 256, 0, stream>>>(B0, W2hi, W2lo, nullptr, B1);
    agg_kernel<128, 2, true, true><<<aggGrid, 256, 0, stream>>>(B1, B2, rp, col, dinv, b2);

    // Layer 3: fp32 GEMM 128->64, aggregate (+bias+relu)
    gemm_kernel<64, 64, 16, 4, 4, false>
        <<<dim3((NNODES + 63) / 64, 1), 256, 0, stream>>>(B2, W3, nullptr, B0, NNODES, 128, 64);
    agg_kernel<64, 1, true, true><<<aggGrid, 256, 0, stream>>>(B0, B1, rp, col, dinv, b3);

    // Layer 4: fp32 GEMM 64->40, aggregate (+bias, no relu) -> out
    gemm_kernel<64, 64, 16, 4, 4, false>
        <<<dim3((NNODES + 63) / 64, 1), 256, 0, stream>>>(B1, W4, nullptr, B0, NNODES, 64, 40);
    agg_kernel<40, 1, false, true><<<aggGrid, 256, 0, stream>>>(B0, out, rp, col, dinv, b4);
}

// Round 4
// 419.599 us; speedup vs baseline: 1.6806x; 1.0775x over previous
//
#include <hip/hip_runtime.h>
#include <stdint.h>

#define NNODES 50000
#define NEDGES 800000
#define SCAN_NBLK ((NNODES + 255) / 256)   // 196

typedef __attribute__((ext_vector_type(8))) short bf16x8;
typedef __attribute__((ext_vector_type(4))) float f32x4;

__device__ inline unsigned short f2bf(float f) {
    unsigned u = __float_as_uint(f);
    return (unsigned short)((u + 0x7fffu + ((u >> 16) & 1u)) >> 16);
}
__device__ inline float bf2f(unsigned short h) {
    return __uint_as_float(((unsigned)h) << 16);
}

// ---------------- CSR build ----------------

__global__ void zero_kernel(int* __restrict__ p, int n) {
    int i = blockIdx.x * blockDim.x + threadIdx.x;
    if (i < n) p[i] = 0;
}

__global__ void count_kernel(const int* __restrict__ dst, int* __restrict__ cnt, int e) {
    int i = blockIdx.x * blockDim.x + threadIdx.x;
    if (i < e) atomicAdd(&cnt[dst[i]], 1);
}

__global__ __launch_bounds__(256) void scan1_kernel(const int* __restrict__ cnt,
                                                    int* __restrict__ bsum) {
    const int i = blockIdx.x * 256 + threadIdx.x;
    int v = (i < NNODES) ? cnt[i] : 0;
#pragma unroll
    for (int off = 32; off > 0; off >>= 1) v += __shfl_down(v, off, 64);
    __shared__ int wsum[4];
    if ((threadIdx.x & 63) == 0) wsum[threadIdx.x >> 6] = v;
    __syncthreads();
    if (threadIdx.x == 0) bsum[blockIdx.x] = wsum[0] + wsum[1] + wsum[2] + wsum[3];
}

__global__ __launch_bounds__(256) void scan2_kernel(const int* __restrict__ bsum,
                                                    int* __restrict__ boff,
                                                    int* __restrict__ rp_last) {
    __shared__ int s[256];
    const int t = threadIdx.x;
    s[t] = (t < SCAN_NBLK) ? bsum[t] : 0;
    __syncthreads();
    for (int off = 1; off < 256; off <<= 1) {
        int v = (t >= off) ? s[t - off] : 0;
        __syncthreads();
        s[t] += v;
        __syncthreads();
    }
    if (t < SCAN_NBLK) boff[t] = (t > 0) ? s[t - 1] : 0;
    if (t == 255) rp_last[0] = s[255];
}

__global__ __launch_bounds__(256) void scan3_kernel(const int* __restrict__ cnt,
                                                    const int* __restrict__ boff,
                                                    int* __restrict__ rp,
                                                    int* __restrict__ cursor,
                                                    float* __restrict__ dinv) {
    __shared__ int s[256];
    const int t = threadIdx.x;
    const int i = blockIdx.x * 256 + t;
    const int c = (i < NNODES) ? cnt[i] : 0;
    s[t] = c;
    __syncthreads();
    for (int off = 1; off < 256; off <<= 1) {
        int v = (t >= off) ? s[t - off] : 0;
        __syncthreads();
        s[t] += v;
        __syncthreads();
    }
    if (i < NNODES) {
        const int excl = boff[blockIdx.x] + s[t] - c;
        rp[i] = excl;
        cursor[i] = excl;
        dinv[i] = rsqrtf((float)(c + 1));
    }
}

__global__ void fill_kernel(const int* __restrict__ src, const int* __restrict__ dst,
                            int* __restrict__ cursor, int* __restrict__ col, int e) {
    int i = blockIdx.x * blockDim.x + threadIdx.x;
    if (i < e) {
        int p = atomicAdd(&cursor[dst[i]], 1);
        col[p] = src[i];
    }
}

// ---------------- fp32 -> bf16 convert (for x mirror) ----------------

__global__ __launch_bounds__(256) void cvt_kernel(const float* __restrict__ in,
                                                  unsigned short* __restrict__ out, int n4) {
    int i = blockIdx.x * 256 + threadIdx.x;
    if (i >= n4) return;
    float4 v = *(const float4*)(in + (size_t)i * 4);
    ushort4 h;
    h.x = f2bf(v.x); h.y = f2bf(v.y); h.z = f2bf(v.z); h.w = f2bf(v.w);
    *(ushort4*)(out + (size_t)i * 4) = h;
}

// ---------------- gather aggregation ----------------
// out[d] = dinv[d] * ( dinv[d]*in32[d]  +  sum_{s in N(d)} dinv[s]*bf16(in)[s] ) [+bias][relu]
// Self term fp32 (coalesced, read once); neighbor gathers from bf16 mirror (half bytes).

template <int VEC>
__device__ inline void vloadf(float (&d)[VEC], const float* __restrict__ p) {
    if constexpr (VEC == 2) { float2 t = *(const float2*)p; d[0]=t.x; d[1]=t.y; }
    else { d[0] = *p; }
}
template <int VEC>
__device__ inline void vloadbf(float (&d)[VEC], const unsigned short* __restrict__ p) {
    if constexpr (VEC == 2) {
        unsigned v = *(const unsigned*)p;
        d[0] = bf2f((unsigned short)(v & 0xffffu));
        d[1] = bf2f((unsigned short)(v >> 16));
    } else {
        d[0] = bf2f(*p);
    }
}
template <int VEC>
__device__ inline void vstoref(float* __restrict__ p, const float (&d)[VEC]) {
    if constexpr (VEC == 2) { *(float2*)p = make_float2(d[0], d[1]); }
    else { *p = d[0]; }
}

template <int F, int VEC, bool RELU, bool HAS_BIAS>
__global__ __launch_bounds__(256) void agg_kernel(const float* __restrict__ in32,
                                                  const unsigned short* __restrict__ inbf,
                                                  float* __restrict__ out,
                                                  const int* __restrict__ rp,
                                                  const int* __restrict__ colidx,
                                                  const float* __restrict__ dinv,
                                                  const float* __restrict__ bias) {
    const int wave = threadIdx.x >> 6;
    const int lane = threadIdx.x & 63;
    const int d = blockIdx.x * 4 + wave;
    if (d >= NNODES) return;
    constexpr int LANES = F / VEC;
    if (lane >= LANES) return;
    const int off = lane * VEC;

    const float dv = dinv[d];
    float acc[VEC];
    vloadf<VEC>(acc, in32 + (size_t)d * F + off);
#pragma unroll
    for (int v = 0; v < VEC; ++v) acc[v] *= dv;

    int j = rp[d];
    const int end = rp[d + 1];
    for (; j + 4 <= end; j += 4) {
        const int c0 = colidx[j + 0], c1 = colidx[j + 1], c2 = colidx[j + 2], c3 = colidx[j + 3];
        const float w0 = dinv[c0], w1 = dinv[c1], w2 = dinv[c2], w3 = dinv[c3];
        float t0[VEC], t1[VEC], t2[VEC], t3[VEC];
        vloadbf<VEC>(t0, inbf + (size_t)c0 * F + off);
        vloadbf<VEC>(t1, inbf + (size_t)c1 * F + off);
        vloadbf<VEC>(t2, inbf + (size_t)c2 * F + off);
        vloadbf<VEC>(t3, inbf + (size_t)c3 * F + off);
#pragma unroll
        for (int v = 0; v < VEC; ++v) acc[v] += w0 * t0[v] + w1 * t1[v] + w2 * t2[v] + w3 * t3[v];
    }
    for (; j < end; ++j) {
        const int c = colidx[j];
        const float wc = dinv[c];
        float t[VEC];
        vloadbf<VEC>(t, inbf + (size_t)c * F + off);
#pragma unroll
        for (int v = 0; v < VEC; ++v) acc[v] += wc * t[v];
    }

    float res[VEC];
#pragma unroll
    for (int v = 0; v < VEC; ++v) {
        float r = dv * acc[v];
        if constexpr (HAS_BIAS) r += bias[off + v];
        if constexpr (RELU) r = fmaxf(r, 0.0f);
        res[v] = r;
    }
    vstoref<VEC>(out + (size_t)d * F + off, res);
}

// ---------------- weight repack: W[K][M] fp32 -> split-bf16 fragment order ----

template <int K, int M>
__global__ __launch_bounds__(256) void repack_kernel(const float* __restrict__ W,
                                                     unsigned short* __restrict__ hi,
                                                     unsigned short* __restrict__ lo) {
    int i = blockIdx.x * 256 + threadIdx.x;
    if (i >= K * M) return;
    const int k = i / M, n = i % M;
    constexpr int KS = K / 32;
    const int cb = n >> 7;
    const int ct = (n >> 4) & 7;
    const int ln = ((k >> 3) & 3) * 16 + (n & 15);
    const int j  = k & 7;
    const int ks = k >> 5;
    const size_t o = ((((size_t)cb * KS + ks) * 8 + ct) * 64 + ln) * 8 + j;
    const float f = W[i];
    const unsigned short h = f2bf(f);
    hi[o] = h;
    lo[o] = f2bf(f - bf2f(h));
}

// ---------------- split-bf16 MFMA GEMM ----------------

template <int K, int M, bool BIAS_RELU, bool WRITE_BF>
__global__ __launch_bounds__(256) void mfma_gemm_kernel(const float* __restrict__ A,
                                                        const unsigned short* __restrict__ Whi,
                                                        const unsigned short* __restrict__ Wlo,
                                                        const float* __restrict__ bias,
                                                        float* __restrict__ C,
                                                        unsigned short* __restrict__ Cbf) {
    constexpr int KS = K / 32;
    __shared__ char lds[32768];
    char* Ahi = lds;
    char* Alo = lds + 8192;
    char* Bhi = lds + 16384;
    char* Blo = lds + 24576;

    const int t = threadIdx.x;
    const int lane = t & 63;
    const int w = t >> 6;
    const int wr = w >> 1, wc = w & 1;
    const int r0 = blockIdx.x * 128;
    const int n0 = blockIdx.y * 128;

    const unsigned short* bhg = Whi + (size_t)blockIdx.y * KS * 4096;
    const unsigned short* blg = Wlo + (size_t)blockIdx.y * KS * 4096;

    f32x4 acc[4][4];
#pragma unroll
    for (int i = 0; i < 4; ++i)
#pragma unroll
        for (int j = 0; j < 4; ++j) acc[i][j] = (f32x4){0.f, 0.f, 0.f, 0.f};

    for (int ks = 0; ks < KS; ++ks) {
        const int k0 = ks * 32;

        {
            const char* gh = (const char*)(bhg + (size_t)ks * 4096);
            const char* gl = (const char*)(blg + (size_t)ks * 4096);
#pragma unroll
            for (int c = 0; c < 2; ++c) {
                const int ct = w * 2 + c;
                __builtin_amdgcn_global_load_lds(
                    (const __attribute__((address_space(1))) void*)(gh + ct * 1024 + lane * 16),
                    (__attribute__((address_space(3))) void*)(Bhi + ct * 1024), 16, 0, 0);
                __builtin_amdgcn_global_load_lds(
                    (const __attribute__((address_space(1))) void*)(gl + ct * 1024 + lane * 16),
                    (__attribute__((address_space(3))) void*)(Blo + ct * 1024), 16, 0, 0);
            }
        }

        float4 av[4];
#pragma unroll
        for (int i = 0; i < 4; ++i) {
            const int q = t + i * 256;
            const int row = q >> 3;
            const int kq = (q & 7) * 4;
            const int gr = r0 + row;
            float4 v = make_float4(0.f, 0.f, 0.f, 0.f);
            if (gr < NNODES) v = *(const float4*)(A + (size_t)gr * K + k0 + kq);
            av[i] = v;
        }
#pragma unroll
        for (int i = 0; i < 4; ++i) {
            const int q = t + i * 256;
            const int row = q >> 3;
            const int kq = (q & 7) * 4;
            const int rt = row >> 4, m = row & 15, quad = kq >> 3, j0 = kq & 7;
            const int off = rt * 1024 + (quad * 16 + m) * 16 + j0 * 2;
            const float4 v = av[i];
            ushort4 h, l;
            h.x = f2bf(v.x); l.x = f2bf(v.x - bf2f(h.x));
            h.y = f2bf(v.y); l.y = f2bf(v.y - bf2f(h.y));
            h.z = f2bf(v.z); l.z = f2bf(v.z - bf2f(h.z));
            h.w = f2bf(v.w); l.w = f2bf(v.w - bf2f(h.w));
            *(ushort4*)(Ahi + off) = h;
            *(ushort4*)(Alo + off) = l;
        }
        __syncthreads();

        bf16x8 ah[4], al[4], bh[4], bl[4];
#pragma unroll
        for (int i = 0; i < 4; ++i) {
            ah[i] = *(const bf16x8*)(Ahi + (wr * 4 + i) * 1024 + lane * 16);
            al[i] = *(const bf16x8*)(Alo + (wr * 4 + i) * 1024 + lane * 16);
            bh[i] = *(const bf16x8*)(Bhi + (wc * 4 + i) * 1024 + lane * 16);
            bl[i] = *(const bf16x8*)(Blo + (wc * 4 + i) * 1024 + lane * 16);
        }
#pragma unroll
        for (int i = 0; i < 4; ++i)
#pragma unroll
            for (int j = 0; j < 4; ++j) {
                acc[i][j] = __builtin_amdgcn_mfma_f32_16x16x32_bf16(ah[i], bh[j], acc[i][j], 0, 0, 0);
                acc[i][j] = __builtin_amdgcn_mfma_f32_16x16x32_bf16(ah[i], bl[j], acc[i][j], 0, 0, 0);
                acc[i][j] = __builtin_amdgcn_mfma_f32_16x16x32_bf16(al[i], bh[j], acc[i][j], 0, 0, 0);
            }
        __syncthreads();
    }

    const int quad = lane >> 4;
    const int cl = lane & 15;
#pragma unroll
    for (int i = 0; i < 4; ++i) {
#pragma unroll
        for (int j = 0; j < 4; ++j) {
            const int colg = n0 + wc * 64 + j * 16 + cl;
            float bv = 0.f;
            if constexpr (BIAS_RELU) bv = bias[colg];
#pragma unroll
            for (int r = 0; r < 4; ++r) {
                const int rowg = r0 + wr * 64 + i * 16 + quad * 4 + r;
                if (rowg < NNODES) {
                    float v = acc[i][j][r] + bv;
                    if constexpr (BIAS_RELU) v = fmaxf(v, 0.f);
                    C[(size_t)rowg * M + colg] = v;
                    if constexpr (WRITE_BF) Cbf[(size_t)rowg * M + colg] = f2bf(v);
                }
            }
        }
    }
}

// ---------------- fp32 register-tiled GEMM (layers 3-4) ----------------

template <int BM, int BN, int BK, int TM, int TN, bool BIAS_RELU, bool WRITE_BF>
__global__ __launch_bounds__(256) void gemm_kernel(const float* __restrict__ A,
                                                   const float* __restrict__ W,
                                                   const float* __restrict__ bias,
                                                   float* __restrict__ C,
                                                   unsigned short* __restrict__ Cbf,
                                                   int Nrows, int K, int M) {
    constexpr int TX = BN / TN;
    constexpr int TY = BM / TM;
    static_assert(TX * TY == 256, "thread grid must be 256");
    constexpr int A_LOADS = (BM * BK) / (256 * 4);
    constexpr int W_LOADS = (BN * BK) / (256 * 4);
    static_assert(A_LOADS >= 1 && W_LOADS >= 1, "tile too small");

    const int tid = threadIdx.x;
    const int tx = tid % TX;
    const int ty = tid / TX;
    const int r0 = blockIdx.x * BM;
    const int c0 = blockIdx.y * BN;

    __shared__ float As[BK][BM + 4];
    __shared__ float Ws[BK][BN];

    float acc[TM][TN] = {};

    for (int k0 = 0; k0 < K; k0 += BK) {
#pragma unroll
        for (int l = 0; l < A_LOADS; ++l) {
            const int idx = tid + l * 256;
            const int row = idx / (BK / 4);
            const int kq = idx % (BK / 4);
            float4 v = make_float4(0.f, 0.f, 0.f, 0.f);
            const int gr = r0 + row;
            if (gr < Nrows) v = *(const float4*)(A + (size_t)gr * K + k0 + kq * 4);
            As[kq * 4 + 0][row] = v.x;
            As[kq * 4 + 1][row] = v.y;
            As[kq * 4 + 2][row] = v.z;
            As[kq * 4 + 3][row] = v.w;
        }
#pragma unroll
        for (int l = 0; l < W_LOADS; ++l) {
            const int idx = tid + l * 256;
            const int kk = idx / (BN / 4);
            const int cq = idx % (BN / 4);
            const int gc = c0 + cq * 4;
            float4 v;
            const float* wrow = W + (size_t)(k0 + kk) * M;
            if (gc + 3 < M) {
                v = *(const float4*)(wrow + gc);
            } else {
                v.x = (gc + 0 < M) ? wrow[gc + 0] : 0.f;
                v.y = (gc + 1 < M) ? wrow[gc + 1] : 0.f;
                v.z = (gc + 2 < M) ? wrow[gc + 2] : 0.f;
                v.w = (gc + 3 < M) ? wrow[gc + 3] : 0.f;
            }
            *(float4*)&Ws[kk][cq * 4] = v;
        }
        __syncthreads();

#pragma unroll
        for (int kk = 0; kk < BK; ++kk) {
            float a[TM], b[TN];
#pragma unroll
            for (int i = 0; i < TM; ++i) a[i] = As[kk][ty * TM + i];
#pragma unroll
            for (int j = 0; j < TN; ++j) b[j] = Ws[kk][tx * TN + j];
#pragma unroll
            for (int i = 0; i < TM; ++i)
#pragma unroll
                for (int j = 0; j < TN; ++j) acc[i][j] += a[i] * b[j];
        }
        __syncthreads();
    }

#pragma unroll
    for (int i = 0; i < TM; ++i) {
        const int gr = r0 + ty * TM + i;
        if (gr >= Nrows) continue;
#pragma unroll
        for (int j = 0; j < TN; ++j) {
            const int gc = c0 + tx * TN + j;
            if (gc >= M) continue;
            float v = acc[i][j];
            if constexpr (BIAS_RELU) v = fmaxf(v + bias[gc], 0.0f);
            C[(size_t)gr * M + gc] = v;
            if constexpr (WRITE_BF) Cbf[(size_t)gr * M + gc] = f2bf(v);
        }
    }
}

// ---------------- launch ----------------

extern "C" void kernel_launch(void* const* d_in, const int* in_sizes, int n_in,
                              void* d_out, int out_size, void* d_ws, size_t ws_size,
                              hipStream_t stream) {
    const float* x  = (const float*)d_in[0];
    const int* ei   = (const int*)d_in[1];
    const float* W1 = (const float*)d_in[2];
    const float* b1 = (const float*)d_in[3];
    const float* W2 = (const float*)d_in[4];
    const float* b2 = (const float*)d_in[5];
    const float* W3 = (const float*)d_in[6];
    const float* b3 = (const float*)d_in[7];
    const float* W4 = (const float*)d_in[8];
    const float* b4 = (const float*)d_in[9];
    float* out = (float*)d_out;
    const int* esrc = ei;
    const int* edst = ei + NEDGES;

    char* w = (char*)d_ws;
    auto alloc = [&](size_t bytes) -> void* {
        void* p = (void*)w;
        w += (bytes + 255) & ~(size_t)255;
        return p;
    };
    int* cnt    = (int*)alloc((size_t)NNODES * 4);
    int* rp     = (int*)alloc((size_t)(NNODES + 1) * 4);
    int* cursor = (int*)alloc((size_t)NNODES * 4);
    int* col    = (int*)alloc((size_t)NEDGES * 4);
    float* dinv = (float*)alloc((size_t)NNODES * 4);
    int* bsum   = (int*)alloc((size_t)SCAN_NBLK * 4);
    int* boff   = (int*)alloc((size_t)SCAN_NBLK * 4);
    unsigned short* W1hi = (unsigned short*)alloc((size_t)128 * 256 * 2);
    unsigned short* W1lo = (unsigned short*)alloc((size_t)128 * 256 * 2);
    unsigned short* W2hi = (unsigned short*)alloc((size_t)256 * 128 * 2);
    unsigned short* W2lo = (unsigned short*)alloc((size_t)256 * 128 * 2);
    float* B0   = (float*)alloc((size_t)NNODES * 256 * 4);
    float* B1   = (float*)alloc((size_t)NNODES * 128 * 4);
    float* B2   = (float*)alloc((size_t)NNODES * 128 * 4);
    unsigned short* xbf  = (unsigned short*)alloc((size_t)NNODES * 128 * 2);  // bf16 mirrors
    unsigned short* B1bf = (unsigned short*)alloc((size_t)NNODES * 128 * 2);
    unsigned short* B0bf = (unsigned short*)alloc((size_t)NNODES * 64 * 2);

    // weight repack + x mirror (tiny)
    repack_kernel<128, 256><<<(128 * 256 + 255) / 256, 256, 0, stream>>>(W1, W1hi, W1lo);
    repack_kernel<256, 128><<<(256 * 128 + 255) / 256, 256, 0, stream>>>(W2, W2hi, W2lo);
    cvt_kernel<<<(NNODES * 128 / 4 + 255) / 256, 256, 0, stream>>>(x, xbf, NNODES * 128 / 4);

    // CSR build
    zero_kernel<<<(NNODES + 255) / 256, 256, 0, stream>>>(cnt, NNODES);
    count_kernel<<<(NEDGES + 255) / 256, 256, 0, stream>>>(edst, cnt, NEDGES);
    scan1_kernel<<<SCAN_NBLK, 256, 0, stream>>>(cnt, bsum);
    scan2_kernel<<<1, 256, 0, stream>>>(bsum, boff, rp + NNODES);
    scan3_kernel<<<SCAN_NBLK, 256, 0, stream>>>(cnt, boff, rp, cursor, dinv);
    fill_kernel<<<(NEDGES + 255) / 256, 256, 0, stream>>>(esrc, edst, cursor, col, NEDGES);

    const int aggGrid = (NNODES + 3) / 4;
    const int rowBlks = (NNODES + 127) / 128;   // 391

    // Layer 1: aggregate first (dim 128, bf16 neighbors), then MFMA GEMM 128->256 (+bias+relu)
    agg_kernel<128, 2, false, false><<<aggGrid, 256, 0, stream>>>(x, xbf, B2, rp, col, dinv, nullptr);
    mfma_gemm_kernel<128, 256, true, false>
        <<<dim3(rowBlks, 2), 256, 0, stream>>>(B2, W1hi, W1lo, b1, B0, nullptr);

    // Layer 2: MFMA GEMM 256->128 (emit bf16 mirror), then aggregate (+bias+relu)
    mfma_gemm_kernel<256, 128, false, true>
        <<<dim3(rowBlks, 1), 256, 0, stream>>>(B0, W2hi, W2lo, nullptr, B1, B1bf);
    agg_kernel<128, 2, true, true><<<aggGrid, 256, 0, stream>>>(B1, B1bf, B2, rp, col, dinv, b2);

    // Layer 3: fp32 GEMM 128->64 (emit bf16 mirror), aggregate (+bias+relu)
    gemm_kernel<64, 64, 16, 4, 4, false, true>
        <<<dim3((NNODES + 63) / 64, 1), 256, 0, stream>>>(B2, W3, nullptr, B0, B0bf, NNODES, 128, 64);
    agg_kernel<64, 1, true, true><<<aggGrid, 256, 0, stream>>>(B0, B0bf, B1, rp, col, dinv, b3);

    // Layer 4: fp32 GEMM 64->40 (emit bf16 mirror), aggregate (+bias, no relu) -> out
    gemm_kernel<64, 64, 16, 4, 4, false, true>
        <<<dim3((NNODES + 63) / 64, 1), 256, 0, stream>>>(B1, W4, nullptr, B0, B0bf, NNODES, 64, 40);
    agg_kernel<40, 1, false, true><<<aggGrid, 256, 0, stream>>>(B0, B0bf, out, rp, col, dinv, b4);
}

// Round 5
// 383.729 us; speedup vs baseline: 1.8377x; 1.0935x over previous
//
#include <hip/hip_runtime.h>
#include <stdint.h>

#define NNODES 50000
#define NEDGES 800000
#define SCAN_NBLK ((NNODES + 255) / 256)   // 196
#define NB ((NNODES + 255) / 256)          // 196 dst-buckets (dst>>8)
#define EPB 4096                           // edges per scatter block
#define SCAT_NBLK ((NEDGES + EPB - 1) / EPB)  // 196

typedef __attribute__((ext_vector_type(8))) short bf16x8;
typedef __attribute__((ext_vector_type(4))) float f32x4;

__device__ inline unsigned short f2bf(float f) {
    unsigned u = __float_as_uint(f);
    return (unsigned short)((u + 0x7fffu + ((u >> 16) & 1u)) >> 16);
}
__device__ inline float bf2f(unsigned short h) {
    return __uint_as_float(((unsigned)h) << 16);
}

// ---------------- bucketed CSR build ----------------

__global__ void zero_kernel(int* __restrict__ p, int n) {
    int i = blockIdx.x * blockDim.x + threadIdx.x;
    if (i < n) p[i] = 0;
}

// Pass 1: per-block LDS histogram over dst>>8 -> global bucket sizes
__global__ __launch_bounds__(256) void bucket_count_kernel(const int* __restrict__ dst,
                                                           int* __restrict__ bhist) {
    __shared__ int h[NB];
    for (int b = threadIdx.x; b < NB; b += 256) h[b] = 0;
    __syncthreads();
    const int base = blockIdx.x * EPB;
#pragma unroll
    for (int i = 0; i < EPB / 256; ++i) {
        const int e = base + threadIdx.x + i * 256;
        if (e < NEDGES) atomicAdd(&h[dst[e] >> 8], 1);
    }
    __syncthreads();
    for (int b = threadIdx.x; b < NB; b += 256)
        if (h[b]) atomicAdd(&bhist[b], h[b]);
}

// Pass 2: single block scans bucket sizes -> bofs (exclusive), gcur = bofs
__global__ __launch_bounds__(256) void bucket_scan_kernel(const int* __restrict__ bhist,
                                                          int* __restrict__ bofs,
                                                          int* __restrict__ gcur) {
    __shared__ int s[256];
    const int t = threadIdx.x;
    s[t] = (t < NB) ? bhist[t] : 0;
    __syncthreads();
    for (int off = 1; off < 256; off <<= 1) {
        int v = (t >= off) ? s[t - off] : 0;
        __syncthreads();
        s[t] += v;
        __syncthreads();
    }
    if (t < NB) {
        const int excl = (t > 0) ? s[t - 1] : 0;
        bofs[t] = excl;
        gcur[t] = excl;
    }
    if (t == 255) bofs[NB] = s[255];
}

// Pass 3: LDS-sort 4096 edges by bucket, write near-coalesced runs per bucket
__global__ __launch_bounds__(256) void bucket_scatter_kernel(const int* __restrict__ src,
                                                             const int* __restrict__ dst,
                                                             int* __restrict__ gcur,
                                                             int2* __restrict__ gpair) {
    __shared__ int h[256];    // counts -> cursors
    __shared__ int s[256];    // inclusive scan -> lofs
    __shared__ int gof[256];
    __shared__ int2 pr[EPB];
    __shared__ int ga[EPB];

    const int t = threadIdx.x;
    const int base = blockIdx.x * EPB;
    const int nval = min(EPB, NEDGES - base);

    h[t] = 0;
    __syncthreads();
#pragma unroll
    for (int i = 0; i < EPB / 256; ++i) {
        const int e = base + t + i * 256;
        if (e < NEDGES) atomicAdd(&h[dst[e] >> 8], 1);
    }
    __syncthreads();
    s[t] = h[t];
    __syncthreads();
    for (int off = 1; off < 256; off <<= 1) {
        int v = (t >= off) ? s[t - off] : 0;
        __syncthreads();
        s[t] += v;
        __syncthreads();
    }
    // reserve global ranges; h becomes local cursor; s becomes lofs
    {
        const int c = h[t];
        if (t < NB && c > 0) gof[t] = atomicAdd(&gcur[t], c);
        const int lofs = s[t] - c;
        h[t] = lofs;
        s[t] = lofs;
    }
    __syncthreads();
#pragma unroll
    for (int i = 0; i < EPB / 256; ++i) {
        const int e = base + t + i * 256;
        if (e < NEDGES) {
            const int d = dst[e];
            const int b = d >> 8;
            const int slot = atomicAdd(&h[b], 1);
            pr[slot] = make_int2(src[e], d);
            ga[slot] = gof[b] + (slot - s[b]);
        }
    }
    __syncthreads();
#pragma unroll
    for (int i = 0; i < EPB / 256; ++i) {
        const int slot = t + i * 256;
        if (slot < nval) gpair[ga[slot]] = pr[slot];
    }
}

// Pass 4a: per-bucket degree count (LDS counters, coalesced cnt write)
__global__ __launch_bounds__(256) void deg_count_kernel(const int2* __restrict__ gpair,
                                                        const int* __restrict__ bofs,
                                                        int* __restrict__ cnt) {
    __shared__ int c[256];
    const int t = threadIdx.x;
    c[t] = 0;
    __syncthreads();
    const int beg = bofs[blockIdx.x], end = bofs[blockIdx.x + 1];
    for (int e = beg + t; e < end; e += 256) atomicAdd(&c[gpair[e].y & 255], 1);
    __syncthreads();
    const int node = blockIdx.x * 256 + t;
    if (node < NNODES) cnt[node] = c[t];
}

// Pass 4b: per-bucket col fill (writes land in L2-hot ~16KB window)
__global__ __launch_bounds__(256) void bucket_fill_kernel(const int2* __restrict__ gpair,
                                                          const int* __restrict__ bofs,
                                                          const int* __restrict__ rp,
                                                          int* __restrict__ col) {
    __shared__ int c[256];
    const int t = threadIdx.x;
    c[t] = 0;
    __syncthreads();
    const int beg = bofs[blockIdx.x], end = bofs[blockIdx.x + 1];
    for (int e = beg + t; e < end; e += 256) {
        const int2 p = gpair[e];
        const int r = atomicAdd(&c[p.y & 255], 1);
        col[rp[p.y] + r] = p.x;
    }
}

// ---------------- node-degree scan (rp, dinv) ----------------

__global__ __launch_bounds__(256) void scan1_kernel(const int* __restrict__ cnt,
                                                    int* __restrict__ bsum) {
    const int i = blockIdx.x * 256 + threadIdx.x;
    int v = (i < NNODES) ? cnt[i] : 0;
#pragma unroll
    for (int off = 32; off > 0; off >>= 1) v += __shfl_down(v, off, 64);
    __shared__ int wsum[4];
    if ((threadIdx.x & 63) == 0) wsum[threadIdx.x >> 6] = v;
    __syncthreads();
    if (threadIdx.x == 0) bsum[blockIdx.x] = wsum[0] + wsum[1] + wsum[2] + wsum[3];
}

__global__ __launch_bounds__(256) void scan2_kernel(const int* __restrict__ bsum,
                                                    int* __restrict__ boff,
                                                    int* __restrict__ rp_last) {
    __shared__ int s[256];
    const int t = threadIdx.x;
    s[t] = (t < SCAN_NBLK) ? bsum[t] : 0;
    __syncthreads();
    for (int off = 1; off < 256; off <<= 1) {
        int v = (t >= off) ? s[t - off] : 0;
        __syncthreads();
        s[t] += v;
        __syncthreads();
    }
    if (t < SCAN_NBLK) boff[t] = (t > 0) ? s[t - 1] : 0;
    if (t == 255) rp_last[0] = s[255];
}

__global__ __launch_bounds__(256) void scan3_kernel(const int* __restrict__ cnt,
                                                    const int* __restrict__ boff,
                                                    int* __restrict__ rp,
                                                    float* __restrict__ dinv) {
    __shared__ int s[256];
    const int t = threadIdx.x;
    const int i = blockIdx.x * 256 + t;
    const int c = (i < NNODES) ? cnt[i] : 0;
    s[t] = c;
    __syncthreads();
    for (int off = 1; off < 256; off <<= 1) {
        int v = (t >= off) ? s[t - off] : 0;
        __syncthreads();
        s[t] += v;
        __syncthreads();
    }
    if (i < NNODES) {
        rp[i] = boff[blockIdx.x] + s[t] - c;
        dinv[i] = rsqrtf((float)(c + 1));
    }
}

// ---------------- fp32 -> bf16 convert (for x mirror) ----------------

__global__ __launch_bounds__(256) void cvt_kernel(const float* __restrict__ in,
                                                  unsigned short* __restrict__ out, int n4) {
    int i = blockIdx.x * 256 + threadIdx.x;
    if (i >= n4) return;
    float4 v = *(const float4*)(in + (size_t)i * 4);
    ushort4 h;
    h.x = f2bf(v.x); h.y = f2bf(v.y); h.z = f2bf(v.z); h.w = f2bf(v.w);
    *(ushort4*)(out + (size_t)i * 4) = h;
}

// ---------------- gather aggregation ----------------

template <int VEC>
__device__ inline void vloadf(float (&d)[VEC], const float* __restrict__ p) {
    if constexpr (VEC == 2) { float2 t = *(const float2*)p; d[0]=t.x; d[1]=t.y; }
    else { d[0] = *p; }
}
template <int VEC>
__device__ inline void vloadbf(float (&d)[VEC], const unsigned short* __restrict__ p) {
    if constexpr (VEC == 2) {
        unsigned v = *(const unsigned*)p;
        d[0] = bf2f((unsigned short)(v & 0xffffu));
        d[1] = bf2f((unsigned short)(v >> 16));
    } else {
        d[0] = bf2f(*p);
    }
}
template <int VEC>
__device__ inline void vstoref(float* __restrict__ p, const float (&d)[VEC]) {
    if constexpr (VEC == 2) { *(float2*)p = make_float2(d[0], d[1]); }
    else { *p = d[0]; }
}

template <int F, int VEC, bool RELU, bool HAS_BIAS>
__global__ __launch_bounds__(256) void agg_kernel(const float* __restrict__ in32,
                                                  const unsigned short* __restrict__ inbf,
                                                  float* __restrict__ out,
                                                  const int* __restrict__ rp,
                                                  const int* __restrict__ colidx,
                                                  const float* __restrict__ dinv,
                                                  const float* __restrict__ bias) {
    const int wave = threadIdx.x >> 6;
    const int lane = threadIdx.x & 63;
    const int d = blockIdx.x * 4 + wave;
    if (d >= NNODES) return;
    constexpr int LANES = F / VEC;
    if (lane >= LANES) return;
    const int off = lane * VEC;

    const float dv = dinv[d];
    float acc[VEC];
    vloadf<VEC>(acc, in32 + (size_t)d * F + off);
#pragma unroll
    for (int v = 0; v < VEC; ++v) acc[v] *= dv;

    int j = rp[d];
    const int end = rp[d + 1];
    for (; j + 4 <= end; j += 4) {
        const int c0 = colidx[j + 0], c1 = colidx[j + 1], c2 = colidx[j + 2], c3 = colidx[j + 3];
        const float w0 = dinv[c0], w1 = dinv[c1], w2 = dinv[c2], w3 = dinv[c3];
        float t0[VEC], t1[VEC], t2[VEC], t3[VEC];
        vloadbf<VEC>(t0, inbf + (size_t)c0 * F + off);
        vloadbf<VEC>(t1, inbf + (size_t)c1 * F + off);
        vloadbf<VEC>(t2, inbf + (size_t)c2 * F + off);
        vloadbf<VEC>(t3, inbf + (size_t)c3 * F + off);
#pragma unroll
        for (int v = 0; v < VEC; ++v) acc[v] += w0 * t0[v] + w1 * t1[v] + w2 * t2[v] + w3 * t3[v];
    }
    for (; j < end; ++j) {
        const int c = colidx[j];
        const float wc = dinv[c];
        float t[VEC];
        vloadbf<VEC>(t, inbf + (size_t)c * F + off);
#pragma unroll
        for (int v = 0; v < VEC; ++v) acc[v] += wc * t[v];
    }

    float res[VEC];
#pragma unroll
    for (int v = 0; v < VEC; ++v) {
        float r = dv * acc[v];
        if constexpr (HAS_BIAS) r += bias[off + v];
        if constexpr (RELU) r = fmaxf(r, 0.0f);
        res[v] = r;
    }
    vstoref<VEC>(out + (size_t)d * F + off, res);
}

// ---------------- weight repack: W[K][M] fp32 -> split-bf16 fragment order ----

template <int K, int M>
__global__ __launch_bounds__(256) void repack_kernel(const float* __restrict__ W,
                                                     unsigned short* __restrict__ hi,
                                                     unsigned short* __restrict__ lo) {
    int i = blockIdx.x * 256 + threadIdx.x;
    if (i >= K * M) return;
    const int k = i / M, n = i % M;
    constexpr int KS = K / 32;
    const int cb = n >> 7;
    const int ct = (n >> 4) & 7;
    const int ln = ((k >> 3) & 3) * 16 + (n & 15);
    const int j  = k & 7;
    const int ks = k >> 5;
    const size_t o = ((((size_t)cb * KS + ks) * 8 + ct) * 64 + ln) * 8 + j;
    const float f = W[i];
    const unsigned short h = f2bf(f);
    hi[o] = h;
    lo[o] = f2bf(f - bf2f(h));
}

// ---------------- split-bf16 MFMA GEMM ----------------

template <int K, int M, bool BIAS_RELU, bool WRITE_BF>
__global__ __launch_bounds__(256) void mfma_gemm_kernel(const float* __restrict__ A,
                                                        const unsigned short* __restrict__ Whi,
                                                        const unsigned short* __restrict__ Wlo,
                                                        const float* __restrict__ bias,
                                                        float* __restrict__ C,
                                                        unsigned short* __restrict__ Cbf) {
    constexpr int KS = K / 32;
    __shared__ char lds[32768];
    char* Ahi = lds;
    char* Alo = lds + 8192;
    char* Bhi = lds + 16384;
    char* Blo = lds + 24576;

    const int t = threadIdx.x;
    const int lane = t & 63;
    const int w = t >> 6;
    const int wr = w >> 1, wc = w & 1;
    const int r0 = blockIdx.x * 128;
    const int n0 = blockIdx.y * 128;

    const unsigned short* bhg = Whi + (size_t)blockIdx.y * KS * 4096;
    const unsigned short* blg = Wlo + (size_t)blockIdx.y * KS * 4096;

    f32x4 acc[4][4];
#pragma unroll
    for (int i = 0; i < 4; ++i)
#pragma unroll
        for (int j = 0; j < 4; ++j) acc[i][j] = (f32x4){0.f, 0.f, 0.f, 0.f};

    for (int ks = 0; ks < KS; ++ks) {
        const int k0 = ks * 32;

        {
            const char* gh = (const char*)(bhg + (size_t)ks * 4096);
            const char* gl = (const char*)(blg + (size_t)ks * 4096);
#pragma unroll
            for (int c = 0; c < 2; ++c) {
                const int ct = w * 2 + c;
                __builtin_amdgcn_global_load_lds(
                    (const __attribute__((address_space(1))) void*)(gh + ct * 1024 + lane * 16),
                    (__attribute__((address_space(3))) void*)(Bhi + ct * 1024), 16, 0, 0);
                __builtin_amdgcn_global_load_lds(
                    (const __attribute__((address_space(1))) void*)(gl + ct * 1024 + lane * 16),
                    (__attribute__((address_space(3))) void*)(Blo + ct * 1024), 16, 0, 0);
            }
        }

        float4 av[4];
#pragma unroll
        for (int i = 0; i < 4; ++i) {
            const int q = t + i * 256;
            const int row = q >> 3;
            const int kq = (q & 7) * 4;
            const int gr = r0 + row;
            float4 v = make_float4(0.f, 0.f, 0.f, 0.f);
            if (gr < NNODES) v = *(const float4*)(A + (size_t)gr * K + k0 + kq);
            av[i] = v;
        }
#pragma unroll
        for (int i = 0; i < 4; ++i) {
            const int q = t + i * 256;
            const int row = q >> 3;
            const int kq = (q & 7) * 4;
            const int rt = row >> 4, m = row & 15, quad = kq >> 3, j0 = kq & 7;
            const int off = rt * 1024 + (quad * 16 + m) * 16 + j0 * 2;
            const float4 v = av[i];
            ushort4 h, l;
            h.x = f2bf(v.x); l.x = f2bf(v.x - bf2f(h.x));
            h.y = f2bf(v.y); l.y = f2bf(v.y - bf2f(h.y));
            h.z = f2bf(v.z); l.z = f2bf(v.z - bf2f(h.z));
            h.w = f2bf(v.w); l.w = f2bf(v.w - bf2f(h.w));
            *(ushort4*)(Ahi + off) = h;
            *(ushort4*)(Alo + off) = l;
        }
        __syncthreads();

        bf16x8 ah[4], al[4], bh[4], bl[4];
#pragma unroll
        for (int i = 0; i < 4; ++i) {
            ah[i] = *(const bf16x8*)(Ahi + (wr * 4 + i) * 1024 + lane * 16);
            al[i] = *(const bf16x8*)(Alo + (wr * 4 + i) * 1024 + lane * 16);
            bh[i] = *(const bf16x8*)(Bhi + (wc * 4 + i) * 1024 + lane * 16);
            bl[i] = *(const bf16x8*)(Blo + (wc * 4 + i) * 1024 + lane * 16);
        }
#pragma unroll
        for (int i = 0; i < 4; ++i)
#pragma unroll
            for (int j = 0; j < 4; ++j) {
                acc[i][j] = __builtin_amdgcn_mfma_f32_16x16x32_bf16(ah[i], bh[j], acc[i][j], 0, 0, 0);
                acc[i][j] = __builtin_amdgcn_mfma_f32_16x16x32_bf16(ah[i], bl[j], acc[i][j], 0, 0, 0);
                acc[i][j] = __builtin_amdgcn_mfma_f32_16x16x32_bf16(al[i], bh[j], acc[i][j], 0, 0, 0);
            }
        __syncthreads();
    }

    const int quad = lane >> 4;
    const int cl = lane & 15;
#pragma unroll
    for (int i = 0; i < 4; ++i) {
#pragma unroll
        for (int j = 0; j < 4; ++j) {
            const int colg = n0 + wc * 64 + j * 16 + cl;
            float bv = 0.f;
            if constexpr (BIAS_RELU) bv = bias[colg];
#pragma unroll
            for (int r = 0; r < 4; ++r) {
                const int rowg = r0 + wr * 64 + i * 16 + quad * 4 + r;
                if (rowg < NNODES) {
                    float v = acc[i][j][r] + bv;
                    if constexpr (BIAS_RELU) v = fmaxf(v, 0.f);
                    C[(size_t)rowg * M + colg] = v;
                    if constexpr (WRITE_BF) Cbf[(size_t)rowg * M + colg] = f2bf(v);
                }
            }
        }
    }
}

// ---------------- fp32 register-tiled GEMM (layers 3-4) ----------------

template <int BM, int BN, int BK, int TM, int TN, bool BIAS_RELU, bool WRITE_BF>
__global__ __launch_bounds__(256) void gemm_kernel(const float* __restrict__ A,
                                                   const float* __restrict__ W,
                                                   const float* __restrict__ bias,
                                                   float* __restrict__ C,
                                                   unsigned short* __restrict__ Cbf,
                                                   int Nrows, int K, int M) {
    constexpr int TX = BN / TN;
    constexpr int TY = BM / TM;
    static_assert(TX * TY == 256, "thread grid must be 256");
    constexpr int A_LOADS = (BM * BK) / (256 * 4);
    constexpr int W_LOADS = (BN * BK) / (256 * 4);
    static_assert(A_LOADS >= 1 && W_LOADS >= 1, "tile too small");

    const int tid = threadIdx.x;
    const int tx = tid % TX;
    const int ty = tid / TX;
    const int r0 = blockIdx.x * BM;
    const int c0 = blockIdx.y * BN;

    __shared__ float As[BK][BM + 4];
    __shared__ float Ws[BK][BN];

    float acc[TM][TN] = {};

    for (int k0 = 0; k0 < K; k0 += BK) {
#pragma unroll
        for (int l = 0; l < A_LOADS; ++l) {
            const int idx = tid + l * 256;
            const int row = idx / (BK / 4);
            const int kq = idx % (BK / 4);
            float4 v = make_float4(0.f, 0.f, 0.f, 0.f);
            const int gr = r0 + row;
            if (gr < Nrows) v = *(const float4*)(A + (size_t)gr * K + k0 + kq * 4);
            As[kq * 4 + 0][row] = v.x;
            As[kq * 4 + 1][row] = v.y;
            As[kq * 4 + 2][row] = v.z;
            As[kq * 4 + 3][row] = v.w;
        }
#pragma unroll
        for (int l = 0; l < W_LOADS; ++l) {
            const int idx = tid + l * 256;
            const int kk = idx / (BN / 4);
            const int cq = idx % (BN / 4);
            const int gc = c0 + cq * 4;
            float4 v;
            const float* wrow = W + (size_t)(k0 + kk) * M;
            if (gc + 3 < M) {
                v = *(const float4*)(wrow + gc);
            } else {
                v.x = (gc + 0 < M) ? wrow[gc + 0] : 0.f;
                v.y = (gc + 1 < M) ? wrow[gc + 1] : 0.f;
                v.z = (gc + 2 < M) ? wrow[gc + 2] : 0.f;
                v.w = (gc + 3 < M) ? wrow[gc + 3] : 0.f;
            }
            *(float4*)&Ws[kk][cq * 4] = v;
        }
        __syncthreads();

#pragma unroll
        for (int kk = 0; kk < BK; ++kk) {
            float a[TM], b[TN];
#pragma unroll
            for (int i = 0; i < TM; ++i) a[i] = As[kk][ty * TM + i];
#pragma unroll
            for (int j = 0; j < TN; ++j) b[j] = Ws[kk][tx * TN + j];
#pragma unroll
            for (int i = 0; i < TM; ++i)
#pragma unroll
                for (int j = 0; j < TN; ++j) acc[i][j] += a[i] * b[j];
        }
        __syncthreads();
    }

#pragma unroll
    for (int i = 0; i < TM; ++i) {
        const int gr = r0 + ty * TM + i;
        if (gr >= Nrows) continue;
#pragma unroll
        for (int j = 0; j < TN; ++j) {
            const int gc = c0 + tx * TN + j;
            if (gc >= M) continue;
            float v = acc[i][j];
            if constexpr (BIAS_RELU) v = fmaxf(v + bias[gc], 0.0f);
            C[(size_t)gr * M + gc] = v;
            if constexpr (WRITE_BF) Cbf[(size_t)gr * M + gc] = f2bf(v);
        }
    }
}

// ---------------- launch ----------------

extern "C" void kernel_launch(void* const* d_in, const int* in_sizes, int n_in,
                              void* d_out, int out_size, void* d_ws, size_t ws_size,
                              hipStream_t stream) {
    const float* x  = (const float*)d_in[0];
    const int* ei   = (const int*)d_in[1];
    const float* W1 = (const float*)d_in[2];
    const float* b1 = (const float*)d_in[3];
    const float* W2 = (const float*)d_in[4];
    const float* b2 = (const float*)d_in[5];
    const float* W3 = (const float*)d_in[6];
    const float* b3 = (const float*)d_in[7];
    const float* W4 = (const float*)d_in[8];
    const float* b4 = (const float*)d_in[9];
    float* out = (float*)d_out;
    const int* esrc = ei;
    const int* edst = ei + NEDGES;

    char* w = (char*)d_ws;
    auto alloc = [&](size_t bytes) -> void* {
        void* p = (void*)w;
        w += (bytes + 255) & ~(size_t)255;
        return p;
    };
    int* cnt    = (int*)alloc((size_t)NNODES * 4);
    int* rp     = (int*)alloc((size_t)(NNODES + 1) * 4);
    int* col    = (int*)alloc((size_t)NEDGES * 4);
    float* dinv = (float*)alloc((size_t)NNODES * 4);
    int* bsum   = (int*)alloc((size_t)SCAN_NBLK * 4);
    int* boff   = (int*)alloc((size_t)SCAN_NBLK * 4);
    int* bhist  = (int*)alloc((size_t)NB * 4);
    int* bofs   = (int*)alloc((size_t)(NB + 1) * 4);
    int* gcur   = (int*)alloc((size_t)NB * 4);
    int2* gpair = (int2*)alloc((size_t)NEDGES * 8);
    unsigned short* W1hi = (unsigned short*)alloc((size_t)128 * 256 * 2);
    unsigned short* W1lo = (unsigned short*)alloc((size_t)128 * 256 * 2);
    unsigned short* W2hi = (unsigned short*)alloc((size_t)256 * 128 * 2);
    unsigned short* W2lo = (unsigned short*)alloc((size_t)256 * 128 * 2);
    float* B0   = (float*)alloc((size_t)NNODES * 256 * 4);
    float* B1   = (float*)alloc((size_t)NNODES * 128 * 4);
    float* B2   = (float*)alloc((size_t)NNODES * 128 * 4);
    unsigned short* xbf  = (unsigned short*)alloc((size_t)NNODES * 128 * 2);
    unsigned short* B1bf = (unsigned short*)alloc((size_t)NNODES * 128 * 2);
    unsigned short* B0bf = (unsigned short*)alloc((size_t)NNODES * 64 * 2);

    // weight repack + x mirror (tiny)
    repack_kernel<128, 256><<<(128 * 256 + 255) / 256, 256, 0, stream>>>(W1, W1hi, W1lo);
    repack_kernel<256, 128><<<(256 * 128 + 255) / 256, 256, 0, stream>>>(W2, W2hi, W2lo);
    cvt_kernel<<<(NNODES * 128 / 4 + 255) / 256, 256, 0, stream>>>(x, xbf, NNODES * 128 / 4);

    // bucketed CSR build
    zero_kernel<<<1, 256, 0, stream>>>(bhist, NB);
    bucket_count_kernel<<<SCAT_NBLK, 256, 0, stream>>>(edst, bhist);
    bucket_scan_kernel<<<1, 256, 0, stream>>>(bhist, bofs, gcur);
    bucket_scatter_kernel<<<SCAT_NBLK, 256, 0, stream>>>(esrc, edst, gcur, gpair);
    deg_count_kernel<<<NB, 256, 0, stream>>>(gpair, bofs, cnt);
    scan1_kernel<<<SCAN_NBLK, 256, 0, stream>>>(cnt, bsum);
    scan2_kernel<<<1, 256, 0, stream>>>(bsum, boff, rp + NNODES);
    scan3_kernel<<<SCAN_NBLK, 256, 0, stream>>>(cnt, boff, rp, dinv);
    bucket_fill_kernel<<<NB, 256, 0, stream>>>(gpair, bofs, rp, col);

    const int aggGrid = (NNODES + 3) / 4;
    const int rowBlks = (NNODES + 127) / 128;   // 391

    // Layer 1: aggregate first (dim 128, bf16 neighbors), then MFMA GEMM 128->256 (+bias+relu)
    agg_kernel<128, 2, false, false><<<aggGrid, 256, 0, stream>>>(x, xbf, B2, rp, col, dinv, nullptr);
    mfma_gemm_kernel<128, 256, true, false>
        <<<dim3(rowBlks, 2), 256, 0, stream>>>(B2, W1hi, W1lo, b1, B0, nullptr);

    // Layer 2: MFMA GEMM 256->128 (emit bf16 mirror), then aggregate (+bias+relu)
    mfma_gemm_kernel<256, 128, false, true>
        <<<dim3(rowBlks, 1), 256, 0, stream>>>(B0, W2hi, W2lo, nullptr, B1, B1bf);
    agg_kernel<128, 2, true, true><<<aggGrid, 256, 0, stream>>>(B1, B1bf, B2, rp, col, dinv, b2);

    // Layer 3: fp32 GEMM 128->64 (emit bf16 mirror), aggregate (+bias+relu)
    gemm_kernel<64, 64, 16, 4, 4, false, true>
        <<<dim3((NNODES + 63) / 64, 1), 256, 0, stream>>>(B2, W3, nullptr, B0, B0bf, NNODES, 128, 64);
    agg_kernel<64, 1, true, true><<<aggGrid, 256, 0, stream>>>(B0, B0bf, B1, rp, col, dinv, b3);

    // Layer 4: fp32 GEMM 64->40 (emit bf16 mirror), aggregate (+bias, no relu) -> out
    gemm_kernel<64, 64, 16, 4, 4, false, true>
        <<<dim3((NNODES + 63) / 64, 1), 256, 0, stream>>>(B1, W4, nullptr, B0, B0bf, NNODES, 64, 40);
    agg_kernel<40, 1, false, true><<<aggGrid, 256, 0, stream>>>(B0, B0bf, out, rp, col, dinv, b4);
}

// Round 6
// 365.932 us; speedup vs baseline: 1.9271x; 1.0486x over previous
//
#include <hip/hip_runtime.h>
#include <stdint.h>

#define NNODES 50000
#define NEDGES 800000
#define NB ((NNODES + 255) / 256)          // 196 dst-buckets (dst>>8); nodes align to buckets
#define EPB 4096                           // edges per scatter block
#define SCAT_NBLK ((NEDGES + EPB - 1) / EPB)  // 196

typedef __attribute__((ext_vector_type(8))) short bf16x8;
typedef __attribute__((ext_vector_type(4))) float f32x4;

__device__ inline unsigned short f2bf(float f) {
    unsigned u = __float_as_uint(f);
    return (unsigned short)((u + 0x7fffu + ((u >> 16) & 1u)) >> 16);
}
__device__ inline float bf2f(unsigned short h) {
    return __uint_as_float(((unsigned)h) << 16);
}

// ---------------- bucketed CSR build ----------------
// src < 65536 so an edge packs as (dst&255)<<16 | src in one uint32.

__global__ void zero_kernel(int* __restrict__ p, int n) {
    int i = blockIdx.x * blockDim.x + threadIdx.x;
    if (i < n) p[i] = 0;
}

// Pass 1: per-block LDS histogram over dst>>8 -> global bucket sizes
__global__ __launch_bounds__(256) void bucket_count_kernel(const int* __restrict__ dst,
                                                           int* __restrict__ bhist) {
    __shared__ int h[NB];
    for (int b = threadIdx.x; b < NB; b += 256) h[b] = 0;
    __syncthreads();
    const int base = blockIdx.x * EPB;
#pragma unroll
    for (int i = 0; i < EPB / 256; ++i) {
        const int e = base + threadIdx.x + i * 256;
        if (e < NEDGES) atomicAdd(&h[dst[e] >> 8], 1);
    }
    __syncthreads();
    for (int b = threadIdx.x; b < NB; b += 256)
        if (h[b]) atomicAdd(&bhist[b], h[b]);
}

// Pass 2: single block scans bucket sizes -> bofs (exclusive), cursors, rp[N]
__global__ __launch_bounds__(256) void bucket_scan_kernel(const int* __restrict__ bhist,
                                                          int* __restrict__ bofs,
                                                          int* __restrict__ gcur,
                                                          int* __restrict__ rp_last) {
    __shared__ int s[256];
    const int t = threadIdx.x;
    s[t] = (t < NB) ? bhist[t] : 0;
    __syncthreads();
    for (int off = 1; off < 256; off <<= 1) {
        int v = (t >= off) ? s[t - off] : 0;
        __syncthreads();
        s[t] += v;
        __syncthreads();
    }
    if (t < NB) {
        const int excl = (t > 0) ? s[t - 1] : 0;
        bofs[t] = excl;
        gcur[t] = excl;
    }
    if (t == 255) { bofs[NB] = s[255]; rp_last[0] = s[255]; }
}

// Pass 3: LDS-sort 4096 edges by bucket, write near-coalesced packed runs
__global__ __launch_bounds__(256) void bucket_scatter_kernel(const int* __restrict__ src,
                                                             const int* __restrict__ dst,
                                                             int* __restrict__ gcur,
                                                             unsigned* __restrict__ gpk) {
    __shared__ int h[256];    // counts -> cursors
    __shared__ int s[256];    // scan -> lofs
    __shared__ int gof[256];
    __shared__ unsigned pr[EPB];
    __shared__ int ga[EPB];

    const int t = threadIdx.x;
    const int base = blockIdx.x * EPB;
    const int nval = min(EPB, NEDGES - base);

    h[t] = 0;
    __syncthreads();
#pragma unroll
    for (int i = 0; i < EPB / 256; ++i) {
        const int e = base + t + i * 256;
        if (e < NEDGES) atomicAdd(&h[dst[e] >> 8], 1);
    }
    __syncthreads();
    s[t] = h[t];
    __syncthreads();
    for (int off = 1; off < 256; off <<= 1) {
        int v = (t >= off) ? s[t - off] : 0;
        __syncthreads();
        s[t] += v;
        __syncthreads();
    }
    {
        const int c = h[t];
        if (t < NB && c > 0) gof[t] = atomicAdd(&gcur[t], c);
        const int lofs = s[t] - c;
        h[t] = lofs;
        s[t] = lofs;
    }
    __syncthreads();
#pragma unroll
    for (int i = 0; i < EPB / 256; ++i) {
        const int e = base + t + i * 256;
        if (e < NEDGES) {
            const int d = dst[e];
            const int b = d >> 8;
            const int slot = atomicAdd(&h[b], 1);
            pr[slot] = ((unsigned)(d & 255) << 16) | (unsigned)src[e];
            ga[slot] = gof[b] + (slot - s[b]);
        }
    }
    __syncthreads();
#pragma unroll
    for (int i = 0; i < EPB / 256; ++i) {
        const int slot = t + i * 256;
        if (slot < nval) gpk[ga[slot]] = pr[slot];
    }
}

// Pass 4: one block per bucket — degree hist, in-bucket scan -> rp/dinv, col fill.
// Works because bucket b holds exactly nodes [256b, 256b+256) and edges are bucket-sorted.
__global__ __launch_bounds__(256) void csr_fill_kernel(const unsigned* __restrict__ gpk,
                                                       const int* __restrict__ bofs,
                                                       int* __restrict__ rp,
                                                       float* __restrict__ dinv,
                                                       int* __restrict__ col) {
    __shared__ int c[256];
    __shared__ int s[256];
    __shared__ int cur[256];
    const int t = threadIdx.x;
    const int b = blockIdx.x;
    const int beg = bofs[b], end = bofs[b + 1];
    c[t] = 0;
    __syncthreads();
    for (int e = beg + t; e < end; e += 256) atomicAdd(&c[gpk[e] >> 16], 1);
    __syncthreads();
    s[t] = c[t];
    __syncthreads();
    for (int off = 1; off < 256; off <<= 1) {
        int v = (t >= off) ? s[t - off] : 0;
        __syncthreads();
        s[t] += v;
        __syncthreads();
    }
    const int excl = s[t] - c[t];
    cur[t] = excl;
    const int node = b * 256 + t;
    if (node < NNODES) {
        rp[node] = beg + excl;
        dinv[node] = rsqrtf((float)(c[t] + 1));   // +1 self loop
    }
    __syncthreads();
    for (int e = beg + t; e < end; e += 256) {
        const unsigned p = gpk[e];
        const int r = atomicAdd(&cur[p >> 16], 1);
        col[beg + r] = (int)(p & 0xffffu);
    }
}

// ---------------- fp32 -> bf16 convert (for x mirror) ----------------

__global__ __launch_bounds__(256) void cvt_kernel(const float* __restrict__ in,
                                                  unsigned short* __restrict__ out, int n4) {
    int i = blockIdx.x * 256 + threadIdx.x;
    if (i >= n4) return;
    float4 v = *(const float4*)(in + (size_t)i * 4);
    ushort4 h;
    h.x = f2bf(v.x); h.y = f2bf(v.y); h.z = f2bf(v.z); h.w = f2bf(v.w);
    *(ushort4*)(out + (size_t)i * 4) = h;
}

// ---------------- gather aggregation ----------------

template <int VEC>
__device__ inline void vloadf(float (&d)[VEC], const float* __restrict__ p) {
    if constexpr (VEC == 2) { float2 t = *(const float2*)p; d[0]=t.x; d[1]=t.y; }
    else { d[0] = *p; }
}
template <int VEC>
__device__ inline void vloadbf(float (&d)[VEC], const unsigned short* __restrict__ p) {
    if constexpr (VEC == 2) {
        unsigned v = *(const unsigned*)p;
        d[0] = bf2f((unsigned short)(v & 0xffffu));
        d[1] = bf2f((unsigned short)(v >> 16));
    } else {
        d[0] = bf2f(*p);
    }
}
template <int VEC>
__device__ inline void vstoref(float* __restrict__ p, const float (&d)[VEC]) {
    if constexpr (VEC == 2) { *(float2*)p = make_float2(d[0], d[1]); }
    else { *p = d[0]; }
}

template <int F, int VEC, bool RELU, bool HAS_BIAS>
__global__ __launch_bounds__(256) void agg_kernel(const float* __restrict__ in32,
                                                  const unsigned short* __restrict__ inbf,
                                                  float* __restrict__ out,
                                                  const int* __restrict__ rp,
                                                  const int* __restrict__ colidx,
                                                  const float* __restrict__ dinv,
                                                  const float* __restrict__ bias) {
    const int wave = threadIdx.x >> 6;
    const int lane = threadIdx.x & 63;
    const int d = blockIdx.x * 4 + wave;
    if (d >= NNODES) return;
    constexpr int LANES = F / VEC;
    if (lane >= LANES) return;
    const int off = lane * VEC;

    const float dv = dinv[d];
    float acc[VEC];
    vloadf<VEC>(acc, in32 + (size_t)d * F + off);
#pragma unroll
    for (int v = 0; v < VEC; ++v) acc[v] *= dv;

    int j = rp[d];
    const int end = rp[d + 1];
    for (; j + 4 <= end; j += 4) {
        const int c0 = colidx[j + 0], c1 = colidx[j + 1], c2 = colidx[j + 2], c3 = colidx[j + 3];
        const float w0 = dinv[c0], w1 = dinv[c1], w2 = dinv[c2], w3 = dinv[c3];
        float t0[VEC], t1[VEC], t2[VEC], t3[VEC];
        vloadbf<VEC>(t0, inbf + (size_t)c0 * F + off);
        vloadbf<VEC>(t1, inbf + (size_t)c1 * F + off);
        vloadbf<VEC>(t2, inbf + (size_t)c2 * F + off);
        vloadbf<VEC>(t3, inbf + (size_t)c3 * F + off);
#pragma unroll
        for (int v = 0; v < VEC; ++v) acc[v] += w0 * t0[v] + w1 * t1[v] + w2 * t2[v] + w3 * t3[v];
    }
    for (; j < end; ++j) {
        const int c = colidx[j];
        const float wc = dinv[c];
        float t[VEC];
        vloadbf<VEC>(t, inbf + (size_t)c * F + off);
#pragma unroll
        for (int v = 0; v < VEC; ++v) acc[v] += wc * t[v];
    }

    float res[VEC];
#pragma unroll
    for (int v = 0; v < VEC; ++v) {
        float r = dv * acc[v];
        if constexpr (HAS_BIAS) r += bias[off + v];
        if constexpr (RELU) r = fmaxf(r, 0.0f);
        res[v] = r;
    }
    vstoref<VEC>(out + (size_t)d * F + off, res);
}

// ---------------- weight repack: W[K][M] fp32 -> split-bf16 fragment order ----

template <int K, int M>
__global__ __launch_bounds__(256) void repack_kernel(const float* __restrict__ W,
                                                     unsigned short* __restrict__ hi,
                                                     unsigned short* __restrict__ lo) {
    int i = blockIdx.x * 256 + threadIdx.x;
    if (i >= K * M) return;
    const int k = i / M, n = i % M;
    constexpr int KS = K / 32;
    const int cb = n >> 7;
    const int ct = (n >> 4) & 7;
    const int ln = ((k >> 3) & 3) * 16 + (n & 15);
    const int j  = k & 7;
    const int ks = k >> 5;
    const size_t o = ((((size_t)cb * KS + ks) * 8 + ct) * 64 + ln) * 8 + j;
    const float f = W[i];
    const unsigned short h = f2bf(f);
    hi[o] = h;
    lo[o] = f2bf(f - bf2f(h));
}

// ---------------- split-bf16 MFMA GEMM ----------------
// BM=128: 4 waves in 2x2, each 64x64.  BM=64: 4 waves in 1x4, each 64x32.

template <int K, int M, int BM, bool BIAS_RELU, bool WRITE_BF>
__global__ __launch_bounds__(256) void mfma_gemm_kernel(const float* __restrict__ A,
                                                        const unsigned short* __restrict__ Whi,
                                                        const unsigned short* __restrict__ Wlo,
                                                        const float* __restrict__ bias,
                                                        float* __restrict__ C,
                                                        unsigned short* __restrict__ Cbf) {
    constexpr int KS = K / 32;
    constexpr int ASZ = BM * 64;                 // bytes per A LDS buffer
    constexpr int CI = (BM == 128) ? 4 : 2;      // col frags per wave
    __shared__ char lds[2 * ASZ + 16384];
    char* Ahi = lds;
    char* Alo = lds + ASZ;
    char* Bhi = lds + 2 * ASZ;
    char* Blo = lds + 2 * ASZ + 8192;

    const int t = threadIdx.x;
    const int lane = t & 63;
    const int w = t >> 6;
    const int wr = (BM == 128) ? (w >> 1) : 0;
    const int wc = (BM == 128) ? (w & 1) : w;
    const int r0 = blockIdx.x * BM;
    const int n0 = blockIdx.y * 128;

    const unsigned short* bhg = Whi + (size_t)blockIdx.y * KS * 4096;
    const unsigned short* blg = Wlo + (size_t)blockIdx.y * KS * 4096;

    f32x4 acc[4][CI];
#pragma unroll
    for (int i = 0; i < 4; ++i)
#pragma unroll
        for (int j = 0; j < CI; ++j) acc[i][j] = (f32x4){0.f, 0.f, 0.f, 0.f};

    for (int ks = 0; ks < KS; ++ks) {
        const int k0 = ks * 32;

        // B tiles: async global->LDS, already in fragment order (8x 1KB chunks per buf)
        {
            const char* gh = (const char*)(bhg + (size_t)ks * 4096);
            const char* gl = (const char*)(blg + (size_t)ks * 4096);
#pragma unroll
            for (int c = 0; c < 2; ++c) {
                const int ct = w * 2 + c;
                __builtin_amdgcn_global_load_lds(
                    (const __attribute__((address_space(1))) void*)(gh + ct * 1024 + lane * 16),
                    (__attribute__((address_space(3))) void*)(Bhi + ct * 1024), 16, 0, 0);
                __builtin_amdgcn_global_load_lds(
                    (const __attribute__((address_space(1))) void*)(gl + ct * 1024 + lane * 16),
                    (__attribute__((address_space(3))) void*)(Blo + ct * 1024), 16, 0, 0);
            }
        }

        // A tile: fp32 global -> split bf16 -> LDS fragment order
        float4 av[BM / 32];
#pragma unroll
        for (int i = 0; i < BM / 32; ++i) {
            const int q = t + i * 256;
            const int row = q >> 3;
            const int kq = (q & 7) * 4;
            const int gr = r0 + row;
            float4 v = make_float4(0.f, 0.f, 0.f, 0.f);
            if (gr < NNODES) v = *(const float4*)(A + (size_t)gr * K + k0 + kq);
            av[i] = v;
        }
#pragma unroll
        for (int i = 0; i < BM / 32; ++i) {
            const int q = t + i * 256;
            const int row = q >> 3;
            const int kq = (q & 7) * 4;
            const int rt = row >> 4, m = row & 15, quad = kq >> 3, j0 = kq & 7;
            const int off = rt * 1024 + (quad * 16 + m) * 16 + j0 * 2;
            const float4 v = av[i];
            ushort4 h, l;
            h.x = f2bf(v.x); l.x = f2bf(v.x - bf2f(h.x));
            h.y = f2bf(v.y); l.y = f2bf(v.y - bf2f(h.y));
            h.z = f2bf(v.z); l.z = f2bf(v.z - bf2f(h.z));
            h.w = f2bf(v.w); l.w = f2bf(v.w - bf2f(h.w));
            *(ushort4*)(Ahi + off) = h;
            *(ushort4*)(Alo + off) = l;
        }
        __syncthreads();

        bf16x8 ah[4], al[4], bh[CI], bl[CI];
#pragma unroll
        for (int i = 0; i < 4; ++i) {
            ah[i] = *(const bf16x8*)(Ahi + (wr * 4 + i) * 1024 + lane * 16);
            al[i] = *(const bf16x8*)(Alo + (wr * 4 + i) * 1024 + lane * 16);
        }
#pragma unroll
        for (int j = 0; j < CI; ++j) {
            bh[j] = *(const bf16x8*)(Bhi + (wc * CI + j) * 1024 + lane * 16);
            bl[j] = *(const bf16x8*)(Blo + (wc * CI + j) * 1024 + lane * 16);
        }
#pragma unroll
        for (int i = 0; i < 4; ++i)
#pragma unroll
            for (int j = 0; j < CI; ++j) {
                acc[i][j] = __builtin_amdgcn_mfma_f32_16x16x32_bf16(ah[i], bh[j], acc[i][j], 0, 0, 0);
                acc[i][j] = __builtin_amdgcn_mfma_f32_16x16x32_bf16(ah[i], bl[j], acc[i][j], 0, 0, 0);
                acc[i][j] = __builtin_amdgcn_mfma_f32_16x16x32_bf16(al[i], bh[j], acc[i][j], 0, 0, 0);
            }
        __syncthreads();
    }

    // epilogue: C/D layout col=lane&15, row=quad*4+reg  [m89-verified]
    const int quad = lane >> 4;
    const int cl = lane & 15;
#pragma unroll
    for (int i = 0; i < 4; ++i) {
#pragma unroll
        for (int j = 0; j < CI; ++j) {
            const int colg = n0 + wc * (CI * 16) + j * 16 + cl;
            float bv = 0.f;
            if constexpr (BIAS_RELU) bv = bias[colg];
#pragma unroll
            for (int r = 0; r < 4; ++r) {
                const int rowg = r0 + wr * 64 + i * 16 + quad * 4 + r;
                if (rowg < NNODES) {
                    float v = acc[i][j][r] + bv;
                    if constexpr (BIAS_RELU) v = fmaxf(v, 0.f);
                    C[(size_t)rowg * M + colg] = v;
                    if constexpr (WRITE_BF) Cbf[(size_t)rowg * M + colg] = f2bf(v);
                }
            }
        }
    }
}

// ---------------- fp32 register-tiled GEMM (layers 3-4) ----------------

template <int BM, int BN, int BK, int TM, int TN, bool BIAS_RELU, bool WRITE_BF>
__global__ __launch_bounds__(256) void gemm_kernel(const float* __restrict__ A,
                                                   const float* __restrict__ W,
                                                   const float* __restrict__ bias,
                                                   float* __restrict__ C,
                                                   unsigned short* __restrict__ Cbf,
                                                   int Nrows, int K, int M) {
    constexpr int TX = BN / TN;
    constexpr int TY = BM / TM;
    static_assert(TX * TY == 256, "thread grid must be 256");
    constexpr int A_LOADS = (BM * BK) / (256 * 4);
    constexpr int W_LOADS = (BN * BK) / (256 * 4);
    static_assert(A_LOADS >= 1 && W_LOADS >= 1, "tile too small");

    const int tid = threadIdx.x;
    const int tx = tid % TX;
    const int ty = tid / TX;
    const int r0 = blockIdx.x * BM;
    const int c0 = blockIdx.y * BN;

    __shared__ float As[BK][BM + 4];
    __shared__ float Ws[BK][BN];

    float acc[TM][TN] = {};

    for (int k0 = 0; k0 < K; k0 += BK) {
#pragma unroll
        for (int l = 0; l < A_LOADS; ++l) {
            const int idx = tid + l * 256;
            const int row = idx / (BK / 4);
            const int kq = idx % (BK / 4);
            float4 v = make_float4(0.f, 0.f, 0.f, 0.f);
            const int gr = r0 + row;
            if (gr < Nrows) v = *(const float4*)(A + (size_t)gr * K + k0 + kq * 4);
            As[kq * 4 + 0][row] = v.x;
            As[kq * 4 + 1][row] = v.y;
            As[kq * 4 + 2][row] = v.z;
            As[kq * 4 + 3][row] = v.w;
        }
#pragma unroll
        for (int l = 0; l < W_LOADS; ++l) {
            const int idx = tid + l * 256;
            const int kk = idx / (BN / 4);
            const int cq = idx % (BN / 4);
            const int gc = c0 + cq * 4;
            float4 v;
            const float* wrow = W + (size_t)(k0 + kk) * M;
            if (gc + 3 < M) {
                v = *(const float4*)(wrow + gc);
            } else {
                v.x = (gc + 0 < M) ? wrow[gc + 0] : 0.f;
                v.y = (gc + 1 < M) ? wrow[gc + 1] : 0.f;
                v.z = (gc + 2 < M) ? wrow[gc + 2] : 0.f;
                v.w = (gc + 3 < M) ? wrow[gc + 3] : 0.f;
            }
            *(float4*)&Ws[kk][cq * 4] = v;
        }
        __syncthreads();

#pragma unroll
        for (int kk = 0; kk < BK; ++kk) {
            float a[TM], b[TN];
#pragma unroll
            for (int i = 0; i < TM; ++i) a[i] = As[kk][ty * TM + i];
#pragma unroll
            for (int j = 0; j < TN; ++j) b[j] = Ws[kk][tx * TN + j];
#pragma unroll
            for (int i = 0; i < TM; ++i)
#pragma unroll
                for (int j = 0; j < TN; ++j) acc[i][j] += a[i] * b[j];
        }
        __syncthreads();
    }

#pragma unroll
    for (int i = 0; i < TM; ++i) {
        const int gr = r0 + ty * TM + i;
        if (gr >= Nrows) continue;
#pragma unroll
        for (int j = 0; j < TN; ++j) {
            const int gc = c0 + tx * TN + j;
            if (gc >= M) continue;
            float v = acc[i][j];
            if constexpr (BIAS_RELU) v = fmaxf(v + bias[gc], 0.0f);
            C[(size_t)gr * M + gc] = v;
            if constexpr (WRITE_BF) Cbf[(size_t)gr * M + gc] = f2bf(v);
        }
    }
}

// ---------------- launch ----------------

extern "C" void kernel_launch(void* const* d_in, const int* in_sizes, int n_in,
                              void* d_out, int out_size, void* d_ws, size_t ws_size,
                              hipStream_t stream) {
    const float* x  = (const float*)d_in[0];
    const int* ei   = (const int*)d_in[1];
    const float* W1 = (const float*)d_in[2];
    const float* b1 = (const float*)d_in[3];
    const float* W2 = (const float*)d_in[4];
    const float* b2 = (const float*)d_in[5];
    const float* W3 = (const float*)d_in[6];
    const float* b3 = (const float*)d_in[7];
    const float* W4 = (const float*)d_in[8];
    const float* b4 = (const float*)d_in[9];
    float* out = (float*)d_out;
    const int* esrc = ei;
    const int* edst = ei + NEDGES;

    char* w = (char*)d_ws;
    auto alloc = [&](size_t bytes) -> void* {
        void* p = (void*)w;
        w += (bytes + 255) & ~(size_t)255;
        return p;
    };
    int* rp     = (int*)alloc((size_t)(NNODES + 1) * 4);
    int* col    = (int*)alloc((size_t)NEDGES * 4);
    float* dinv = (float*)alloc((size_t)NNODES * 4);
    int* bhist  = (int*)alloc((size_t)NB * 4);
    int* bofs   = (int*)alloc((size_t)(NB + 1) * 4);
    int* gcur   = (int*)alloc((size_t)NB * 4);
    unsigned* gpk = (unsigned*)alloc((size_t)NEDGES * 4);
    unsigned short* W1hi = (unsigned short*)alloc((size_t)128 * 256 * 2);
    unsigned short* W1lo = (unsigned short*)alloc((size_t)128 * 256 * 2);
    unsigned short* W2hi = (unsigned short*)alloc((size_t)256 * 128 * 2);
    unsigned short* W2lo = (unsigned short*)alloc((size_t)256 * 128 * 2);
    float* B0   = (float*)alloc((size_t)NNODES * 256 * 4);
    float* B1   = (float*)alloc((size_t)NNODES * 128 * 4);
    float* B2   = (float*)alloc((size_t)NNODES * 128 * 4);
    unsigned short* xbf  = (unsigned short*)alloc((size_t)NNODES * 128 * 2);
    unsigned short* B1bf = (unsigned short*)alloc((size_t)NNODES * 128 * 2);
    unsigned short* B0bf = (unsigned short*)alloc((size_t)NNODES * 64 * 2);

    // weight repack + x mirror (tiny)
    repack_kernel<128, 256><<<(128 * 256 + 255) / 256, 256, 0, stream>>>(W1, W1hi, W1lo);
    repack_kernel<256, 128><<<(256 * 128 + 255) / 256, 256, 0, stream>>>(W2, W2hi, W2lo);
    cvt_kernel<<<(NNODES * 128 / 4 + 255) / 256, 256, 0, stream>>>(x, xbf, NNODES * 128 / 4);

    // bucketed CSR build (5 dispatches)
    zero_kernel<<<1, 256, 0, stream>>>(bhist, NB);
    bucket_count_kernel<<<SCAT_NBLK, 256, 0, stream>>>(edst, bhist);
    bucket_scan_kernel<<<1, 256, 0, stream>>>(bhist, bofs, gcur, rp + NNODES);
    bucket_scatter_kernel<<<SCAT_NBLK, 256, 0, stream>>>(esrc, edst, gcur, gpk);
    csr_fill_kernel<<<NB, 256, 0, stream>>>(gpk, bofs, rp, dinv, col);

    const int aggGrid = (NNODES + 3) / 4;
    const int rowBlks64 = (NNODES + 63) / 64;   // 782

    // Layer 1: aggregate first (dim 128, bf16 neighbors), then MFMA GEMM 128->256 (+bias+relu)
    agg_kernel<128, 2, false, false><<<aggGrid, 256, 0, stream>>>(x, xbf, B2, rp, col, dinv, nullptr);
    mfma_gemm_kernel<128, 256, 64, true, false>
        <<<dim3(rowBlks64, 2), 256, 0, stream>>>(B2, W1hi, W1lo, b1, B0, nullptr);

    // Layer 2: MFMA GEMM 256->128 (emit bf16 mirror), then aggregate (+bias+relu)
    mfma_gemm_kernel<256, 128, 64, false, true>
        <<<dim3(rowBlks64, 1), 256, 0, stream>>>(B0, W2hi, W2lo, nullptr, B1, B1bf);
    agg_kernel<128, 2, true, true><<<aggGrid, 256, 0, stream>>>(B1, B1bf, B2, rp, col, dinv, b2);

    // Layer 3: fp32 GEMM 128->64 (emit bf16 mirror), aggregate (+bias+relu)
    gemm_kernel<64, 64, 16, 4, 4, false, true>
        <<<dim3(rowBlks64, 1), 256, 0, stream>>>(B2, W3, nullptr, B0, B0bf, NNODES, 128, 64);
    agg_kernel<64, 1, true, true><<<aggGrid, 256, 0, stream>>>(B0, B0bf, B1, rp, col, dinv, b3);

    // Layer 4: fp32 GEMM 64->40 (emit bf16 mirror), aggregate (+bias, no relu) -> out
    gemm_kernel<64, 64, 16, 4, 4, false, true>
        <<<dim3(rowBlks64, 1), 256, 0, stream>>>(B1, W4, nullptr, B0, B0bf, NNODES, 64, 40);
    agg_kernel<40, 1, false, true><<<aggGrid, 256, 0, stream>>>(B0, B0bf, out, rp, col, dinv, b4);
}